// Round 3
// baseline (269.420 us; speedup 1.0000x reference)
//
#include <hip/hip_runtime.h>
#include <hip/hip_bf16.h>
#include <math.h>

#define T 4096
#define E 64
#define NH 8
#define BHN 16
#define NB 64   // buckets per sequence
#define BS 64   // bucket size

using bf16x8 = __attribute__((ext_vector_type(8))) short;
using f32x4  = __attribute__((ext_vector_type(4))) float;

__device__ __forceinline__ f32x4 mfma16(bf16x8 a, bf16x8 b, f32x4 c) {
  return __builtin_amdgcn_mfma_f32_16x16x32_bf16(a, b, c, 0, 0, 0);
}

__device__ __forceinline__ unsigned short f2bf(float x) {
  unsigned u = __float_as_uint(x);
  unsigned r = u + 0x7fff + ((u >> 16) & 1);
  return (unsigned short)(r >> 16);
}
__device__ __forceinline__ float bf2f(unsigned short b) {
  return __uint_as_float(((unsigned)b) << 16);
}
__device__ __forceinline__ float f4get(const float4& v, int i) {
  return i == 0 ? v.x : i == 1 ? v.y : i == 2 ? v.z : v.w;
}

// async global->LDS, 16B per lane, linear dest (wave-uniform base + lane*16)
__device__ __forceinline__ void async_load16(const void* src, void* dst_lds) {
  __builtin_amdgcn_global_load_lds(
      (const __attribute__((address_space(1))) unsigned int*)src,
      (__attribute__((address_space(3))) unsigned int*)dst_lds, 16, 0, 0);
}

#define DW(v, k) ((k) == 0 ? (v).x : (k) == 1 ? (v).y : (k) == 2 ? (v).z : (v).w)

// byte-offset swizzles: rows of 128B / 256B, XOR row bits into 16B-slot bits
#define SWZ128(row, inb) ((((row)) << 7) + ((inb) ^ ((((row)) & 7) << 4)))
#define SWZ256(row, inb) ((((row)) << 8) + ((inb) ^ ((((row)) & 7) << 4)))

// ---------------------------------------------------------------------------
// K_prep (fast path): per (bh, token): norm, k_hat hi/lo bf16, v hi/lo bf16.
// grid (T/64, BH), block 256 (4 threads per token, 16 elems each).
// ---------------------------------------------------------------------------
__global__ __launch_bounds__(256) void k_prep(const float* __restrict__ qk,
                                              const float* __restrict__ v,
                                              unsigned short* __restrict__ khi,
                                              unsigned short* __restrict__ klo,
                                              unsigned short* __restrict__ vhi,
                                              unsigned short* __restrict__ vlo,
                                              float* __restrict__ norm025) {
  const int tid = threadIdx.x;
  const int tok = blockIdx.x * 64 + (tid >> 2);
  const int bh = blockIdx.y;
  const int b = bh >> 3, hh = bh & 7;
  const int q4 = tid & 3;
  const size_t g = ((size_t)b * T + tok) * 512 + hh * 64 + q4 * 16;

  float4 x[4], y[4];
  #pragma unroll
  for (int k = 0; k < 4; ++k) {
    x[k] = *(const float4*)&qk[g + k * 4];
    y[k] = *(const float4*)&v[g + k * 4];
  }
  float ss = 0.f;
  #pragma unroll
  for (int k = 0; k < 4; ++k)
    ss += x[k].x * x[k].x + x[k].y * x[k].y + x[k].z * x[k].z + x[k].w * x[k].w;
  ss += __shfl_xor(ss, 1);
  ss += __shfl_xor(ss, 2);
  const float nrm = sqrtf(ss);
  const float invn = 1.0f / nrm;

  const size_t ob = ((size_t)bh * T + tok) * 64 + q4 * 16;

  unsigned kh[8], kl[8], vh[8], vl[8];
  #pragma unroll
  for (int k = 0; k < 4; ++k) {
    #pragma unroll
    for (int p = 0; p < 2; ++p) {
      float a0 = f4get(x[k], 2 * p) * invn, a1 = f4get(x[k], 2 * p + 1) * invn;
      unsigned short h0 = f2bf(a0), h1 = f2bf(a1);
      unsigned short l0 = f2bf(a0 - bf2f(h0)), l1 = f2bf(a1 - bf2f(h1));
      kh[k * 2 + p] = (unsigned)h0 | ((unsigned)h1 << 16);
      kl[k * 2 + p] = (unsigned)l0 | ((unsigned)l1 << 16);
      float b0 = f4get(y[k], 2 * p), b1 = f4get(y[k], 2 * p + 1);
      unsigned short g0 = f2bf(b0), g1 = f2bf(b1);
      unsigned short m0 = f2bf(b0 - bf2f(g0)), m1 = f2bf(b1 - bf2f(g1));
      vh[k * 2 + p] = (unsigned)g0 | ((unsigned)g1 << 16);
      vl[k * 2 + p] = (unsigned)m0 | ((unsigned)m1 << 16);
    }
  }
  *(uint4*)&khi[ob]     = (uint4){kh[0], kh[1], kh[2], kh[3]};
  *(uint4*)&khi[ob + 8] = (uint4){kh[4], kh[5], kh[6], kh[7]};
  *(uint4*)&klo[ob]     = (uint4){kl[0], kl[1], kl[2], kl[3]};
  *(uint4*)&klo[ob + 8] = (uint4){kl[4], kl[5], kl[6], kl[7]};
  *(uint4*)&vhi[ob]     = (uint4){vh[0], vh[1], vh[2], vh[3]};
  *(uint4*)&vhi[ob + 8] = (uint4){vh[4], vh[5], vh[6], vh[7]};
  *(uint4*)&vlo[ob]     = (uint4){vl[0], vl[1], vl[2], vl[3]};
  *(uint4*)&vlo[ob + 8] = (uint4){vl[4], vl[5], vl[6], vl[7]};
  if (q4 == 0) norm025[(size_t)bh * T + tok] = 0.125f * nrm;
}

// ---------------------------------------------------------------------------
// K1 fast: LSH buckets, one hash per block-z (round-1 structure, full occup).
// grid (T/64, BH, NH), block 64.
// ---------------------------------------------------------------------------
__global__ __launch_bounds__(64) void k_bucket_fast(const float* __restrict__ qk,
                                                    const float* __restrict__ rot,
                                                    unsigned char* __restrict__ buckets) {
  __shared__ float sQ[64][65];
  const int tid = threadIdx.x;
  const int t0 = blockIdx.x * 64;
  const int bh = blockIdx.y;
  const int r  = blockIdx.z;
  const int b = bh >> 3, hh = bh & 7;
  const size_t gbase = (size_t)b * ((size_t)T * 512) + (size_t)hh * 64;

  for (int k = 0; k < 64; ++k)
    sQ[k][tid] = qk[gbase + (size_t)(t0 + k) * 512 + tid];
  __syncthreads();

  const int t = t0 + tid;
  float acc[32];
  #pragma unroll
  for (int i = 0; i < 32; ++i) acc[i] = 0.f;
  for (int f = 0; f < 64; ++f) {
    float qv = sQ[tid][f];
    const float* rp = rot + (size_t)f * (NH * 32) + r * 32;
    #pragma unroll
    for (int i = 0; i < 32; ++i) acc[i] += qv * rp[i];
  }
  float maxv = -INFINITY, minv = INFINITY;
  int amax = 0, amin = 0;
  #pragma unroll
  for (int i = 0; i < 32; ++i) {
    if (acc[i] > maxv) { maxv = acc[i]; amax = i; }
    if (acc[i] < minv) { minv = acc[i]; amin = i; }
  }
  int bucket = (maxv >= -minv) ? amax : 32 + amin;
  buckets[((size_t)r * BHN + bh) * T + t] = (unsigned char)bucket;
}

// ---------------------------------------------------------------------------
// K1 fallback: buckets (8 hashes folded) + inv_norm (round-2 version).
// ---------------------------------------------------------------------------
__global__ __launch_bounds__(64) void k_bucket_fb(const float* __restrict__ qk,
                                                  const float* __restrict__ rot,
                                                  unsigned char* __restrict__ buckets,
                                                  float* __restrict__ inv_norm) {
  __shared__ float sQ[64][65];
  const int tid = threadIdx.x;
  const int t0 = blockIdx.x * 64;
  const int bh = blockIdx.y;
  const int b = bh >> 3, hh = bh & 7;
  const size_t gbase = (size_t)b * ((size_t)T * 512) + (size_t)hh * 64;

  for (int k = 0; k < 64; ++k)
    sQ[k][tid] = qk[gbase + (size_t)(t0 + k) * 512 + tid];
  __syncthreads();

  const int t = t0 + tid;
  float ss = 0.f;
  #pragma unroll
  for (int f = 0; f < 64; ++f) { float q = sQ[tid][f]; ss += q * q; }
  inv_norm[bh * T + t] = 1.0f / sqrtf(ss);

  for (int r = 0; r < NH; ++r) {
    float acc[32];
    #pragma unroll
    for (int i = 0; i < 32; ++i) acc[i] = 0.f;
    for (int f = 0; f < 64; ++f) {
      float qv = sQ[tid][f];
      const float* rp = rot + (size_t)f * (NH * 32) + r * 32;
      #pragma unroll
      for (int i = 0; i < 32; ++i) acc[i] += qv * rp[i];
    }
    float maxv = -INFINITY, minv = INFINITY;
    int amax = 0, amin = 0;
    #pragma unroll
    for (int i = 0; i < 32; ++i) {
      if (acc[i] > maxv) { maxv = acc[i]; amax = i; }
      if (acc[i] < minv) { minv = acc[i]; amin = i; }
    }
    int bucket = (maxv >= -minv) ? amax : 32 + amin;
    buckets[((size_t)r * BHN + bh) * T + t] = (unsigned char)bucket;
  }
}

// ---------------------------------------------------------------------------
// K2: stable counting argsort per (hash, bh) segment. grid (NH*BH), block 1024.
// ---------------------------------------------------------------------------
__global__ __launch_bounds__(1024) void k_sort(const unsigned char* __restrict__ buckets,
                                               int* __restrict__ perm) {
  __shared__ unsigned short bkt[T];
  __shared__ unsigned short rnk[T];
  __shared__ unsigned int cnt[64 * 64];
  __shared__ unsigned int bbase[64];
  __shared__ unsigned int btot[64];

  const int tid = threadIdx.x;
  const int seg = blockIdx.x;
  const unsigned char* bin = buckets + (size_t)seg * T;

  for (int idx = tid; idx < T; idx += 1024) bkt[idx] = bin[idx];
  __syncthreads();

  const int wave = tid >> 6, lane = tid & 63;
  const unsigned long long lt = (1ull << lane) - 1ull;
  for (int cc = 0; cc < 4; ++cc) {
    int chunk = wave * 4 + cc;
    int e = bkt[chunk * 64 + lane];
    for (int bb = 0; bb < 64; ++bb) {
      unsigned long long m = __ballot(e == bb);
      if (lane == bb) cnt[bb * 64 + chunk] = (unsigned int)__popcll(m);
      if (e == bb) rnk[chunk * 64 + lane] = (unsigned short)__popcll(m & lt);
    }
  }
  __syncthreads();
  if (tid < 64) {
    unsigned int run = 0;
    for (int c = 0; c < 64; ++c) {
      unsigned int v = cnt[tid * 64 + c];
      cnt[tid * 64 + c] = run;
      run += v;
    }
    btot[tid] = run;
  }
  __syncthreads();
  if (tid == 0) {
    unsigned int run = 0;
    for (int bb = 0; bb < 64; ++bb) { bbase[bb] = run; run += btot[bb]; }
  }
  __syncthreads();
  for (int idx = tid; idx < T; idx += 1024) {
    int e = bkt[idx];
    int c = idx >> 6;
    int pos = (int)(bbase[e] + cnt[e * 64 + c] + rnk[idx]);
    perm[(size_t)seg * T + pos] = idx;
  }
}

// ---------------------------------------------------------------------------
// K3 fast: per-bucket attention, S^T orientation, Q==K trick, preconverted
// bf16 inputs. grid (NB, BH, NH), block 256 (4 waves).
// ---------------------------------------------------------------------------
__global__ __launch_bounds__(256) void k_attn_fast(
    const unsigned short* __restrict__ khi, const unsigned short* __restrict__ klo,
    const unsigned short* __restrict__ vhi, const unsigned short* __restrict__ vlo,
    const int* __restrict__ perm, const float* __restrict__ norm025,
    float* __restrict__ o_ws, float* __restrict__ lse_ws) {
  __shared__ __align__(16) char smem[49664];
  constexpr int LKH = 0;        // Khat hi [128 rows][128B] (SWZ128)
  constexpr int LKL = 16384;    // Khat lo [128][128B]
  constexpr int LVH = 32768;    // V^T hi [64][256B] (SWZ256)
  constexpr int LIDX = 49152;   // 128 ints
  // overlays: P -> LKH as [64][256B]; V^T lo -> LKL as [64][256B]; O -> LVH
  int* sIdx = (int*)(smem + LIDX);

  const int tid = threadIdx.x;
  const int n = blockIdx.x, bh = blockIdx.y, r = blockIdx.z;
  const size_t ps = ((size_t)r * BHN + bh) * T;
  const size_t rowbase = (size_t)bh * T;

  if (tid < 128) {
    int src = (tid < 64) ? (n * 64 + tid) : (((n + 63) & 63) * 64 + (tid - 64));
    sIdx[tid] = perm[ps + src];
  }
  __syncthreads();  // s1

  const int wid = tid >> 6, lane = tid & 63;
  const int lr = lane & 15, lg = lane >> 4;

  const int qtok = sIdx[16 * wid + lr];
  const float scale = norm025[rowbase + qtok];

  // ---- V gather to regs (hi/lo), consumed after QK ----
  const int vt0 = (tid & 31) * 4, vd0 = (tid >> 5) * 8;
  uint4 VH[4], VL[4];
  #pragma unroll
  for (int j = 0; j < 4; ++j) {
    size_t vb = (rowbase + (size_t)sIdx[vt0 + j]) * 64 + vd0;
    VH[j] = *(const uint4*)&vhi[vb];
    VL[j] = *(const uint4*)&vlo[vb];
  }

  // ---- K staging: global_load_lds, linear dest + source-swizzled slots ----
  #pragma unroll
  for (int it = 0; it < 4; ++it) {
    int unit = it * 256 + tid;        // 16B unit
    int row = unit >> 3, sl = unit & 7;
    int ssl = sl ^ (row & 7);
    size_t gb = (rowbase + (size_t)sIdx[row]) * 64 + ssl * 8;
    async_load16(&khi[gb], smem + LKH + unit * 16);
    async_load16(&klo[gb], smem + LKL + unit * 16);
  }
  __syncthreads();  // s2 (drains vmcnt)

  // ---- QK: S^T = Khat(all 128) . Khat(q rows)^T, 3-chain 2-term ----
  bf16x8 bqh[2], bql[2];
  #pragma unroll
  for (int ks = 0; ks < 2; ++ks) {
    bqh[ks] = *(const bf16x8*)(smem + LKH + SWZ128(16 * wid + lr, lg * 16 + ks * 64));
    bql[ks] = *(const bf16x8*)(smem + LKL + SWZ128(16 * wid + lr, lg * 16 + ks * 64));
  }
  f32x4 c[8];
  #pragma unroll
  for (int t = 0; t < 8; ++t) c[t] = (f32x4){0.f, 0.f, 0.f, 0.f};
  #pragma unroll
  for (int t = 0; t < 8; ++t) {
    #pragma unroll
    for (int ks = 0; ks < 2; ++ks) {
      bf16x8 ah = *(const bf16x8*)(smem + LKH + SWZ128(16 * t + lr, lg * 16 + ks * 64));
      bf16x8 al = *(const bf16x8*)(smem + LKL + SWZ128(16 * t + lr, lg * 16 + ks * 64));
      c[t] = mfma16(ah, bqh[ks], c[t]);
      c[t] = mfma16(al, bqh[ks], c[t]);
      c[t] = mfma16(ah, bql[ks], c[t]);
    }
  }

  // ---- V^T hi: register 4x8 16-bit transpose into own LDS region ----
  #pragma unroll
  for (int dd = 0; dd < 8; ++dd) {
    const int jd = dd >> 1;
    unsigned w0, w1;
    if (dd & 1) {
      w0 = __builtin_amdgcn_perm(DW(VH[1], jd), DW(VH[0], jd), 0x07060302u);
      w1 = __builtin_amdgcn_perm(DW(VH[3], jd), DW(VH[2], jd), 0x07060302u);
    } else {
      w0 = __builtin_amdgcn_perm(DW(VH[1], jd), DW(VH[0], jd), 0x05040100u);
      w1 = __builtin_amdgcn_perm(DW(VH[3], jd), DW(VH[2], jd), 0x05040100u);
    }
    *(uint2*)(smem + LVH + SWZ256(vd0 + dd, vt0 * 2)) = make_uint2(w0, w1);
  }

  // ---- self-mask: kv position == q position (exact diagonal) ----
  #pragma unroll
  for (int t = 0; t < 4; ++t) {
    #pragma unroll
    for (int rr = 0; rr < 4; ++rr)
      if (16 * t + 4 * lg + rr == 16 * wid + lr) c[t][rr] = -1e30f;
  }

  // ---- softmax over 32 in-lane values + lanes xor16/32 (same q = 16w+lr) ----
  float mm = -1e30f;
  #pragma unroll
  for (int t = 0; t < 8; ++t)
    mm = fmaxf(mm, fmaxf(fmaxf(c[t][0], c[t][1]), fmaxf(c[t][2], c[t][3])));
  mm = fmaxf(mm, __shfl_xor(mm, 16));
  mm = fmaxf(mm, __shfl_xor(mm, 32));
  const float sl2e = scale * 1.4426950408889634f;
  float ll = 0.f;
  #pragma unroll
  for (int t = 0; t < 8; ++t) {
    #pragma unroll
    for (int rr = 0; rr < 4; ++rr) {
      float e = exp2f((c[t][rr] - mm) * sl2e);
      c[t][rr] = e;
      ll += e;
    }
  }
  ll += __shfl_xor(ll, 16);
  ll += __shfl_xor(ll, 32);

  if (lg == 0) lse_ws[ps + qtok] = scale * mm + __logf(ll);

  __syncthreads();  // s3: all K reads done; LKH/LKL reusable

  // ---- P (unnormalized, bf16) over LKH as [64 q][256B] ----
  {
    const int row = 16 * wid + lr;
    #pragma unroll
    for (int t = 0; t < 8; ++t) {
      __hip_bfloat162 p01 = __float22bfloat162_rn(make_float2(c[t][0], c[t][1]));
      __hip_bfloat162 p23 = __float22bfloat162_rn(make_float2(c[t][2], c[t][3]));
      unsigned u01, u23;
      __builtin_memcpy(&u01, &p01, 4);
      __builtin_memcpy(&u23, &p23, 4);
      *(uint2*)(smem + LKH + SWZ256(row, 32 * t + 8 * lg)) = make_uint2(u01, u23);
    }
  }
  // ---- V^T lo over LKL as [64 d][256B] ----
  #pragma unroll
  for (int dd = 0; dd < 8; ++dd) {
    const int jd = dd >> 1;
    unsigned w0, w1;
    if (dd & 1) {
      w0 = __builtin_amdgcn_perm(DW(VL[1], jd), DW(VL[0], jd), 0x07060302u);
      w1 = __builtin_amdgcn_perm(DW(VL[3], jd), DW(VL[2], jd), 0x07060302u);
    } else {
      w0 = __builtin_amdgcn_perm(DW(VL[1], jd), DW(VL[0], jd), 0x05040100u);
      w1 = __builtin_amdgcn_perm(DW(VL[3], jd), DW(VL[2], jd), 0x05040100u);
    }
    *(uint2*)(smem + LKL + SWZ256(vd0 + dd, vt0 * 2)) = make_uint2(w0, w1);
  }
  __syncthreads();  // s4: P + V^T staged

  // ---- PV: A = P rows (q = 16w+lr), B = V^T (hi + lo) ----
  bf16x8 pa[4];
  #pragma unroll
  for (int ks = 0; ks < 4; ++ks)
    pa[ks] = *(const bf16x8*)(smem + LKH + SWZ256(16 * wid + lr, lg * 16 + ks * 64));
  f32x4 o[4];
  #pragma unroll
  for (int t = 0; t < 4; ++t) o[t] = (f32x4){0.f, 0.f, 0.f, 0.f};
  #pragma unroll
  for (int t = 0; t < 4; ++t) {
    #pragma unroll
    for (int ks = 0; ks < 4; ++ks) {
      bf16x8 bvh = *(const bf16x8*)(smem + LVH + SWZ256(16 * t + lr, lg * 16 + ks * 64));
      o[t] = mfma16(pa[ks], bvh, o[t]);
      bf16x8 bvl = *(const bf16x8*)(smem + LKL + SWZ256(16 * t + lr, lg * 16 + ks * 64));
      o[t] = mfma16(pa[ks], bvl, o[t]);
    }
  }

  // ---- normalize by l (per output q-row = 16w + 4lg + rr) ----
  float rl[4];
  #pragma unroll
  for (int rr = 0; rr < 4; ++rr) rl[rr] = 1.0f / __shfl(ll, 4 * lg + rr);
  #pragma unroll
  for (int t = 0; t < 4; ++t)
    #pragma unroll
    for (int rr = 0; rr < 4; ++rr) o[t][rr] *= rl[rr];

  __syncthreads();  // s5: all PV LDS reads done
  // ---- O stage fp32 over LVH [64 q][256B], then coalesced scatter ----
  #pragma unroll
  for (int t = 0; t < 4; ++t)
    #pragma unroll
    for (int rr = 0; rr < 4; ++rr)
      *(float*)(smem + LVH + SWZ256(16 * wid + 4 * lg + rr, (16 * t + lr) * 4)) = o[t][rr];
  __syncthreads();  // s6
  {
    const int row = tid >> 2, cq = tid & 3;
    const int tt = sIdx[row];
    size_t gb = (ps + (size_t)tt) * 64 + cq * 16;
    #pragma unroll
    for (int cc = 0; cc < 4; ++cc)
      *(float4*)&o_ws[gb + cc * 4] =
          *(const float4*)(smem + LVH + SWZ256(row, cq * 64 + cc * 16));
  }
}

// ---------------------------------------------------------------------------
// K3 fallback: round-2 proven kernel (fp32 inputs, in-kernel conversion).
// ---------------------------------------------------------------------------
__global__ __launch_bounds__(256) void k_attn_fb(const float* __restrict__ qk,
                                                 const float* __restrict__ vglob,
                                                 const int* __restrict__ perm,
                                                 const float* __restrict__ inv_norm,
                                                 float* __restrict__ o_ws,
                                                 float* __restrict__ lse_ws) {
  __shared__ __align__(16) char smem[49664];
  constexpr int LQHI = 0;
  constexpr int LQLO = 8192;
  constexpr int LKHI = 16384;
  constexpr int LVTLO = 32768;
  constexpr int LIDX = 49152;
  constexpr int LP   = 0;
  constexpr int LVTHI = 16384;
  constexpr int LO   = 0;
  int* sIdx = (int*)(smem + LIDX);

  const int tid = threadIdx.x;
  const int n = blockIdx.x, bh = blockIdx.y, r = blockIdx.z;
  const int b = bh >> 3, hh = bh & 7;
  const size_t gbase = (size_t)b * ((size_t)T * 512) + (size_t)hh * 64;
  const size_t ps = ((size_t)r * BHN + bh) * T;

  if (tid < 128) {
    int src = (tid < 64) ? (n * 64 + tid) : (((n + 63) & 63) * 64 + (tid - 64));
    sIdx[tid] = perm[ps + src];
  }
  __syncthreads();

  #pragma unroll
  for (int it = 0; it < 8; ++it) {
    int idx = it * 256 + tid;
    int tok = idx >> 4;
    int f0 = (idx & 15) * 4;
    int tt = sIdx[tok];
    float4 x = *(const float4*)&qk[gbase + (size_t)tt * 512 + f0];
    float inr = inv_norm[bh * T + tt];
    ushort4 kh;
    kh.x = f2bf(x.x * inr); kh.y = f2bf(x.y * inr);
    kh.z = f2bf(x.z * inr); kh.w = f2bf(x.w * inr);
    *(ushort4*)(smem + LKHI + SWZ128(tok, f0 * 2)) = kh;
    if (it < 4) {
      float q0 = x.x * 0.125f, q1 = x.y * 0.125f, q2 = x.z * 0.125f, q3 = x.w * 0.125f;
      ushort4 qh, ql;
      qh.x = f2bf(q0); ql.x = f2bf(q0 - bf2f(qh.x));
      qh.y = f2bf(q1); ql.y = f2bf(q1 - bf2f(qh.y));
      qh.z = f2bf(q2); ql.z = f2bf(q2 - bf2f(qh.z));
      qh.w = f2bf(q3); ql.w = f2bf(q3 - bf2f(qh.w));
      *(ushort4*)(smem + LQHI + SWZ128(tok, f0 * 2)) = qh;
      *(ushort4*)(smem + LQLO + SWZ128(tok, f0 * 2)) = ql;
    }
  }

  float4 vreg[8];
  #pragma unroll
  for (int bb = 0; bb < 2; ++bb) {
    int blkid = bb * 256 + tid;
    int tok0 = (blkid & 31) * 4, d0 = (blkid >> 5) * 4;
    #pragma unroll
    for (int jj = 0; jj < 4; ++jj)
      vreg[bb * 4 + jj] = *(const float4*)&vglob[gbase + (size_t)sIdx[tok0 + jj] * 512 + d0];
  }
  __syncthreads();

  const int wid = tid >> 6, lane = tid & 63;
  const int lr = lane & 15, lg = lane >> 4;

  bf16x8 a_hi[2], a_lo[2];
  #pragma unroll
  for (int ks = 0; ks < 2; ++ks) {
    a_hi[ks] = *(const bf16x8*)(smem + LQHI + SWZ128(16 * wid + lr, lg * 16 + ks * 64));
    a_lo[ks] = *(const bf16x8*)(smem + LQLO + SWZ128(16 * wid + lr, lg * 16 + ks * 64));
  }
  __syncthreads();

  f32x4 c[8];
  #pragma unroll
  for (int t = 0; t < 8; ++t) c[t] = (f32x4){0.f, 0.f, 0.f, 0.f};
  #pragma unroll
  for (int t = 0; t < 8; ++t) {
    #pragma unroll
    for (int ks = 0; ks < 2; ++ks) {
      bf16x8 bk = *(const bf16x8*)(smem + LKHI + SWZ128(16 * t + lr, lg * 16 + ks * 64));
      c[t] = mfma16(a_hi[ks], bk, c[t]);
      c[t] = mfma16(a_lo[ks], bk, c[t]);
    }
  }

  int qi[4];
  #pragma unroll
  for (int q = 0; q < 4; ++q) qi[q] = sIdx[16 * wid + 4 * lg + q];
  #pragma unroll
  for (int t = 0; t < 8; ++t) {
    int kt = sIdx[16 * t + lr];
    #pragma unroll
    for (int q = 0; q < 4; ++q)
      if (kt == qi[q]) c[t][q] = -50000.0f;
  }

  float pm[4], pl[4];
  #pragma unroll
  for (int q = 0; q < 4; ++q) {
    float mm = c[0][q];
    #pragma unroll
    for (int t = 1; t < 8; ++t) mm = fmaxf(mm, c[t][q]);
    mm = fmaxf(mm, __shfl_xor(mm, 1));
    mm = fmaxf(mm, __shfl_xor(mm, 2));
    mm = fmaxf(mm, __shfl_xor(mm, 4));
    mm = fmaxf(mm, __shfl_xor(mm, 8));
    float ss = 0.f;
    #pragma unroll
    for (int t = 0; t < 8; ++t) { float e = __expf(c[t][q] - mm); c[t][q] = e; ss += e; }
    ss += __shfl_xor(ss, 1);
    ss += __shfl_xor(ss, 2);
    ss += __shfl_xor(ss, 4);
    ss += __shfl_xor(ss, 8);
    pm[q] = mm; pl[q] = ss;
  }

  __hip_bfloat16* sP = (__hip_bfloat16*)smem;
  #pragma unroll
  for (int q = 0; q < 4; ++q) {
    float rcp = 1.0f / pl[q];
    int row = 16 * wid + 4 * lg + q;
    #pragma unroll
    for (int t = 0; t < 8; ++t)
      *(unsigned short*)(smem + LP + SWZ256(row, (16 * t + lr) * 2)) =
          f2bf(c[t][q] * rcp);
    if (lr == 0)
      lse_ws[ps + qi[q]] = pm[q] + __logf(pl[q]);
  }
  (void)sP;
  #pragma unroll
  for (int bb = 0; bb < 2; ++bb) {
    int blkid = bb * 256 + tid;
    int tok0 = (blkid & 31) * 4, d0 = (blkid >> 5) * 4;
    #pragma unroll
    for (int dd = 0; dd < 4; ++dd) {
      ushort4 hi, lo;
      float x0 = f4get(vreg[bb * 4 + 0], dd);
      float x1 = f4get(vreg[bb * 4 + 1], dd);
      float x2 = f4get(vreg[bb * 4 + 2], dd);
      float x3 = f4get(vreg[bb * 4 + 3], dd);
      hi.x = f2bf(x0); lo.x = f2bf(x0 - bf2f(hi.x));
      hi.y = f2bf(x1); lo.y = f2bf(x1 - bf2f(hi.y));
      hi.z = f2bf(x2); lo.z = f2bf(x2 - bf2f(hi.z));
      hi.w = f2bf(x3); lo.w = f2bf(x3 - bf2f(hi.w));
      *(ushort4*)(smem + LVTHI + SWZ256(d0 + dd, tok0 * 2)) = hi;
      *(ushort4*)(smem + LVTLO + SWZ256(d0 + dd, tok0 * 2)) = lo;
    }
  }
  __syncthreads();

  bf16x8 pa[4];
  #pragma unroll
  for (int ks = 0; ks < 4; ++ks)
    pa[ks] = *(const bf16x8*)(smem + LP + SWZ256(16 * wid + lr, lg * 16 + ks * 64));
  f32x4 o[4];
  #pragma unroll
  for (int t = 0; t < 4; ++t) o[t] = (f32x4){0.f, 0.f, 0.f, 0.f};
  #pragma unroll
  for (int t = 0; t < 4; ++t) {
    #pragma unroll
    for (int ks = 0; ks < 4; ++ks) {
      bf16x8 bhv = *(const bf16x8*)(smem + LVTHI + SWZ256(16 * t + lr, lg * 16 + ks * 64));
      o[t] = mfma16(pa[ks], bhv, o[t]);
      bf16x8 blv = *(const bf16x8*)(smem + LVTLO + SWZ256(16 * t + lr, lg * 16 + ks * 64));
      o[t] = mfma16(pa[ks], blv, o[t]);
    }
  }
  __syncthreads();

  #pragma unroll
  for (int t = 0; t < 4; ++t) {
    #pragma unroll
    for (int q = 0; q < 4; ++q)
      *(float*)(smem + LO + SWZ256(16 * wid + 4 * lg + q, (16 * t + lr) * 4)) = o[t][q];
  }
  __syncthreads();

  {
    int row = tid >> 2, cq = tid & 3;
    int tt = sIdx[row];
    size_t gb = (ps + (size_t)tt) * 64 + cq * 16;
    #pragma unroll
    for (int cc = 0; cc < 4; ++cc) {
      float4 val = *(const float4*)(smem + LO + SWZ256(row, cq * 64 + cc * 16));
      *(float4*)&o_ws[gb + cc * 4] = val;
    }
  }
}

// ---------------------------------------------------------------------------
// K4: combine hashes. grid (BH*T*64/256), block 256.
// ---------------------------------------------------------------------------
__global__ __launch_bounds__(256) void k_combine(const float* __restrict__ o_ws,
                                                 const float* __restrict__ lse_ws,
                                                 float* __restrict__ out) {
  const int gid = blockIdx.x * 256 + threadIdx.x;
  const int d = gid & 63;
  const int row = gid >> 6;
  const int bh = row >> 12;
  const int t = row & (T - 1);

  float ls[8];
  float mm = -INFINITY;
  #pragma unroll
  for (int r = 0; r < 8; ++r) {
    ls[r] = lse_ws[((size_t)r * BHN + bh) * T + t];
    mm = fmaxf(mm, ls[r]);
  }
  float sum = 0.f;
  #pragma unroll
  for (int r = 0; r < 8; ++r) { ls[r] = __expf(ls[r] - mm); sum += ls[r]; }
  float rcp = 1.0f / sum;

  float acc = 0.f;
  #pragma unroll
  for (int r = 0; r < 8; ++r)
    acc += ls[r] * o_ws[(((size_t)r * BHN + bh) * T + t) * 64 + d];
  acc *= rcp;

  const int b = bh >> 3, hh = bh & 7;
  out[(((size_t)b * T + t) * 8 + hh) * 64 + d] = acc;
}

// ---------------------------------------------------------------------------
extern "C" void kernel_launch(void* const* d_in, const int* in_sizes, int n_in,
                              void* d_out, int out_size, void* d_ws, size_t ws_size,
                              hipStream_t stream) {
  const float* qk  = (const float*)d_in[0];
  const float* v   = (const float*)d_in[1];
  const float* rot = (const float*)d_in[2];
  float* out = (float*)d_out;

  char* ws = (char*)d_ws;
  float* o_ws           = (float*)(ws);                      // 134217728
  int* perm             = (int*)(ws + 134217728);            // 8388608
  unsigned char* bkts   = (unsigned char*)(ws + 142606336);  // 524288
  float* lse_ws         = (float*)(ws + 143130624);          // 2097152
  float* norm025        = (float*)(ws + 145227776);          // 262144
  float* inv_norm       = (float*)(ws + 145489920);          // 262144
  unsigned short* khi   = (unsigned short*)(ws + 145752064); // 33554432
  unsigned short* klo   = (unsigned short*)(ws + 179306496); // 33554432
  unsigned short* vhi   = (unsigned short*)(ws + 212860928); // 33554432
  unsigned short* vlo   = (unsigned short*)(ws + 246415360); // 33554432
  // fast path total: 279969792 bytes

  const bool fast = (ws_size >= 279969792ull);

  if (fast) {
    k_prep<<<dim3(T / 64, BHN), 256, 0, stream>>>(qk, v, khi, klo, vhi, vlo, norm025);
    k_bucket_fast<<<dim3(T / 64, BHN, NH), 64, 0, stream>>>(qk, rot, bkts);
    k_sort<<<dim3(NH * BHN), 1024, 0, stream>>>(bkts, perm);
    k_attn_fast<<<dim3(NB, BHN, NH), 256, 0, stream>>>(khi, klo, vhi, vlo, perm,
                                                       norm025, o_ws, lse_ws);
  } else {
    k_bucket_fb<<<dim3(T / 64, BHN), 64, 0, stream>>>(qk, rot, bkts, inv_norm);
    k_sort<<<dim3(NH * BHN), 1024, 0, stream>>>(bkts, perm);
    k_attn_fb<<<dim3(NB, BHN, NH), 256, 0, stream>>>(qk, v, perm, inv_norm, o_ws, lse_ws);
  }
  k_combine<<<dim3((BHN * T * 64) / 256), 256, 0, stream>>>(o_ws, lse_ws, out);
}

// Round 4
// 218.673 us; speedup vs baseline: 1.2321x; 1.2321x over previous
//
#include <hip/hip_runtime.h>
#include <hip/hip_bf16.h>
#include <math.h>

#define T 4096
#define NH 8
#define BHN 16
#define NB 64   // buckets per sequence
#define BS 64   // bucket size

using bf16x8 = __attribute__((ext_vector_type(8))) short;
using f32x4  = __attribute__((ext_vector_type(4))) float;

__device__ __forceinline__ f32x4 mfma16(bf16x8 a, bf16x8 b, f32x4 c) {
  return __builtin_amdgcn_mfma_f32_16x16x32_bf16(a, b, c, 0, 0, 0);
}

// packed fp32x2 -> bf16x2 (RNE), returns uint with elem0 in low half
__device__ __forceinline__ unsigned cvtpk(float a, float b) {
  __hip_bfloat162 p = __float22bfloat162_rn(make_float2(a, b));
  unsigned u; __builtin_memcpy(&u, &p, 4); return u;
}
// recover the two rounded fp32 values from a packed pair
__device__ __forceinline__ float pk0f(unsigned h) { return __uint_as_float(h << 16); }
__device__ __forceinline__ float pk1f(unsigned h) { return __uint_as_float(h & 0xffff0000u); }
__device__ __forceinline__ float f4get(const float4& v, int i) {
  return i == 0 ? v.x : i == 1 ? v.y : i == 2 ? v.z : v.w;
}

// byte-offset swizzles: rows of 128B / 256B, XOR row bits into 16B-slot bits
#define SWZ128(row, inb) ((((row)) << 7) + ((inb) ^ ((((row)) & 7) << 4)))
#define SWZ256(row, inb) ((((row)) << 8) + ((inb) ^ ((((row)) & 7) << 4)))

// ---------------------------------------------------------------------------
// K1: LSH buckets, one hash per block-z; z==0 also writes inv_norm + norm025.
// grid (T/64, BH, NH), block 64.
// ---------------------------------------------------------------------------
__global__ __launch_bounds__(64) void k_bucket(const float* __restrict__ qk,
                                               const float* __restrict__ rot,
                                               unsigned char* __restrict__ buckets,
                                               float* __restrict__ inv_norm,
                                               float* __restrict__ norm025) {
  __shared__ float sQ[64][65];
  const int tid = threadIdx.x;
  const int t0 = blockIdx.x * 64;
  const int bh = blockIdx.y;
  const int r  = blockIdx.z;
  const int b = bh >> 3, hh = bh & 7;
  const size_t gbase = (size_t)b * ((size_t)T * 512) + (size_t)hh * 64;

  for (int k = 0; k < 64; ++k)
    sQ[k][tid] = qk[gbase + (size_t)(t0 + k) * 512 + tid];
  __syncthreads();

  const int t = t0 + tid;
  if (r == 0) {
    float ss = 0.f;
    #pragma unroll
    for (int f = 0; f < 64; ++f) { float q = sQ[tid][f]; ss += q * q; }
    float in = rsqrtf(ss);
    inv_norm[(size_t)bh * T + t] = in;
    norm025[(size_t)bh * T + t] = 0.125f * ss * in;  // 0.125*||qk||
  }

  float acc[32];
  #pragma unroll
  for (int i = 0; i < 32; ++i) acc[i] = 0.f;
  for (int f = 0; f < 64; ++f) {
    float qv = sQ[tid][f];
    const float* rp = rot + (size_t)f * (NH * 32) + r * 32;
    #pragma unroll
    for (int i = 0; i < 32; ++i) acc[i] += qv * rp[i];
  }
  float maxv = -INFINITY, minv = INFINITY;
  int amax = 0, amin = 0;
  #pragma unroll
  for (int i = 0; i < 32; ++i) {
    if (acc[i] > maxv) { maxv = acc[i]; amax = i; }
    if (acc[i] < minv) { minv = acc[i]; amin = i; }
  }
  int bucket = (maxv >= -minv) ? amax : 32 + amin;
  buckets[((size_t)r * BHN + bh) * T + t] = (unsigned char)bucket;
}

// ---------------------------------------------------------------------------
// K2: stable counting argsort per (hash, bh) segment. grid (NH*BH), block 1024.
// ---------------------------------------------------------------------------
__global__ __launch_bounds__(1024) void k_sort(const unsigned char* __restrict__ buckets,
                                               int* __restrict__ perm) {
  __shared__ unsigned short bkt[T];
  __shared__ unsigned short rnk[T];
  __shared__ unsigned int cnt[64 * 64];
  __shared__ unsigned int bbase[64];
  __shared__ unsigned int btot[64];

  const int tid = threadIdx.x;
  const int seg = blockIdx.x;
  const unsigned char* bin = buckets + (size_t)seg * T;

  for (int idx = tid; idx < T; idx += 1024) bkt[idx] = bin[idx];
  __syncthreads();

  const int wave = tid >> 6, lane = tid & 63;
  const unsigned long long lt = (1ull << lane) - 1ull;
  for (int cc = 0; cc < 4; ++cc) {
    int chunk = wave * 4 + cc;
    int e = bkt[chunk * 64 + lane];
    for (int bb = 0; bb < 64; ++bb) {
      unsigned long long m = __ballot(e == bb);
      if (lane == bb) cnt[bb * 64 + chunk] = (unsigned int)__popcll(m);
      if (e == bb) rnk[chunk * 64 + lane] = (unsigned short)__popcll(m & lt);
    }
  }
  __syncthreads();
  if (tid < 64) {
    unsigned int run = 0;
    for (int c = 0; c < 64; ++c) {
      unsigned int v = cnt[tid * 64 + c];
      cnt[tid * 64 + c] = run;
      run += v;
    }
    btot[tid] = run;
  }
  __syncthreads();
  if (tid == 0) {
    unsigned int run = 0;
    for (int bb = 0; bb < 64; ++bb) { bbase[bb] = run; run += btot[bb]; }
  }
  __syncthreads();
  for (int idx = tid; idx < T; idx += 1024) {
    int e = bkt[idx];
    int c = idx >> 6;
    int pos = (int)(bbase[e] + cnt[e * 64 + c] + rnk[idx]);
    perm[(size_t)seg * T + pos] = idx;
  }
}

// ---------------------------------------------------------------------------
// K3: per-bucket attention. Q==K trick (q = 0.125*||qk||*k_hat): S^T = Khat.Khat_q^T
// with 2-term bf16 (3-MFMA chain); per-row scale folded into exponent/lse.
// grid (NB, BH, NH), block 256 (4 waves).
// ---------------------------------------------------------------------------
__global__ __launch_bounds__(256, 3) void k_attn3(
    const float* __restrict__ qk, const float* __restrict__ vglob,
    const int* __restrict__ perm, const float* __restrict__ inv_norm,
    const float* __restrict__ norm025,
    float* __restrict__ o_ws, float* __restrict__ lse_ws) {
  __shared__ __align__(16) char smem[49664];
  constexpr int LKH = 0;        // Khat hi [128 rows][128B] (SWZ128); overlay: P [64][256B]
  constexpr int LKL = 16384;    // Khat lo [128][128B];      overlay: V^T lo [64][256B]
  constexpr int LVH = 32768;    // V^T hi [64][256B];        overlay: O fp32 [64][256B]
  constexpr int LIDX = 49152;   // 128 ints
  int* sIdx = (int*)(smem + LIDX);

  const int tid = threadIdx.x;
  const int n = blockIdx.x, bh = blockIdx.y, r = blockIdx.z;
  const int b = bh >> 3, hh = bh & 7;
  const size_t gbase = (size_t)b * ((size_t)T * 512) + (size_t)hh * 64;
  const size_t rowbase = (size_t)bh * T;
  const size_t ps = ((size_t)r * BHN + bh) * T;

  if (tid < 128) {
    int src = (tid < 64) ? (n * 64 + tid) : (((n + 63) & 63) * 64 + (tid - 64));
    sIdx[tid] = perm[ps + src];
  }
  __syncthreads();  // s1

  // ---- V gather (fp32) into regs; stays in flight across K staging + QK ----
  const int vt0 = (tid & 31) * 4, vd0 = (tid >> 5) * 8;
  float4 vr[8];
  #pragma unroll
  for (int j = 0; j < 4; ++j) {
    const float* src = &vglob[gbase + (size_t)sIdx[vt0 + j] * 512 + vd0];
    vr[2 * j]     = *(const float4*)src;
    vr[2 * j + 1] = *(const float4*)(src + 4);
  }

  // ---- K̂ staging: normalize + bf16 hi/lo, 16B units (8 elems/unit) ----
  #pragma unroll
  for (int it = 0; it < 4; ++it) {
    int idx = it * 256 + tid;
    int row = idx >> 3, u = idx & 7;
    int tok = sIdx[row];
    float inr = inv_norm[rowbase + tok];
    const float* src = &qk[gbase + (size_t)tok * 512 + u * 8];
    float4 x0 = *(const float4*)src, x1 = *(const float4*)(src + 4);
    x0.x *= inr; x0.y *= inr; x0.z *= inr; x0.w *= inr;
    x1.x *= inr; x1.y *= inr; x1.z *= inr; x1.w *= inr;
    unsigned h0 = cvtpk(x0.x, x0.y), h1 = cvtpk(x0.z, x0.w);
    unsigned h2 = cvtpk(x1.x, x1.y), h3 = cvtpk(x1.z, x1.w);
    unsigned l0 = cvtpk(x0.x - pk0f(h0), x0.y - pk1f(h0));
    unsigned l1 = cvtpk(x0.z - pk0f(h1), x0.w - pk1f(h1));
    unsigned l2 = cvtpk(x1.x - pk0f(h2), x1.y - pk1f(h2));
    unsigned l3 = cvtpk(x1.z - pk0f(h3), x1.w - pk1f(h3));
    *(uint4*)(smem + LKH + SWZ128(row, u * 16)) = (uint4){h0, h1, h2, h3};
    *(uint4*)(smem + LKL + SWZ128(row, u * 16)) = (uint4){l0, l1, l2, l3};
  }
  __syncthreads();  // s2

  const int wid = tid >> 6, lane = tid & 63;
  const int lr = lane & 15, lg = lane >> 4;
  const int qtok = sIdx[16 * wid + lr];
  const float scale = norm025[rowbase + qtok];

  // B frags = own q row of Khat (held in regs; LKH will be overlaid by P)
  bf16x8 bqh[2], bql[2];
  #pragma unroll
  for (int ks = 0; ks < 2; ++ks) {
    bqh[ks] = *(const bf16x8*)(smem + LKH + SWZ128(16 * wid + lr, lg * 16 + ks * 64));
    bql[ks] = *(const bf16x8*)(smem + LKL + SWZ128(16 * wid + lr, lg * 16 + ks * 64));
  }

  // ---- QK: S^T[kv][q], 2-term x 2-term via 3 chains ----
  f32x4 c[8];
  #pragma unroll
  for (int t = 0; t < 8; ++t) c[t] = (f32x4){0.f, 0.f, 0.f, 0.f};
  #pragma unroll
  for (int t = 0; t < 8; ++t) {
    #pragma unroll
    for (int ks = 0; ks < 2; ++ks) {
      bf16x8 ah = *(const bf16x8*)(smem + LKH + SWZ128(16 * t + lr, lg * 16 + ks * 64));
      bf16x8 al = *(const bf16x8*)(smem + LKL + SWZ128(16 * t + lr, lg * 16 + ks * 64));
      c[t] = mfma16(ah, bqh[ks], c[t]);
      c[t] = mfma16(al, bqh[ks], c[t]);
      c[t] = mfma16(ah, bql[ks], c[t]);
    }
  }

  // ---- V^T hi -> LVH (own region, hidden under QK); keep packed hi in regs ----
  unsigned vhp[16];
  #pragma unroll
  for (int d = 0; d < 8; ++d) {
    float v0 = f4get(vr[0 + (d >> 2)], d & 3);
    float v1 = f4get(vr[2 + (d >> 2)], d & 3);
    float v2 = f4get(vr[4 + (d >> 2)], d & 3);
    float v3 = f4get(vr[6 + (d >> 2)], d & 3);
    unsigned a = cvtpk(v0, v1), bb = cvtpk(v2, v3);
    vhp[2 * d] = a; vhp[2 * d + 1] = bb;
    *(uint2*)(smem + LVH + SWZ256(vd0 + d, vt0 * 2)) = make_uint2(a, bb);
  }

  // ---- self-mask: position diagonal (own-bucket rows are kv 0..63) ----
  #pragma unroll
  for (int t = 0; t < 4; ++t) {
    #pragma unroll
    for (int rr = 0; rr < 4; ++rr)
      if (16 * t + 4 * lg + rr == 16 * wid + lr) c[t][rr] = -1e30f;
  }

  // ---- softmax (fixed q = 16*wid+lr per lane; reduce over lanes xor16/32) ----
  float mm = -1e30f;
  #pragma unroll
  for (int t = 0; t < 8; ++t)
    mm = fmaxf(mm, fmaxf(fmaxf(c[t][0], c[t][1]), fmaxf(c[t][2], c[t][3])));
  mm = fmaxf(mm, __shfl_xor(mm, 16));
  mm = fmaxf(mm, __shfl_xor(mm, 32));
  const float sl2e = scale * 1.4426950408889634f;
  float ll = 0.f;
  #pragma unroll
  for (int t = 0; t < 8; ++t) {
    #pragma unroll
    for (int rr = 0; rr < 4; ++rr) {
      float e = exp2f((c[t][rr] - mm) * sl2e);
      c[t][rr] = e;
      ll += e;
    }
  }
  ll += __shfl_xor(ll, 16);
  ll += __shfl_xor(ll, 32);
  if (lg == 0) lse_ws[ps + qtok] = scale * mm + __logf(ll);

  __syncthreads();  // s3: all Khat reads done

  // ---- P (unnormalized bf16) over LKH as [64 q][256B] ----
  {
    const int row = 16 * wid + lr;
    #pragma unroll
    for (int t = 0; t < 8; ++t) {
      unsigned u01 = cvtpk(c[t][0], c[t][1]);
      unsigned u23 = cvtpk(c[t][2], c[t][3]);
      *(uint2*)(smem + LKH + SWZ256(row, 32 * t + 8 * lg)) = make_uint2(u01, u23);
    }
  }
  // ---- V^T lo over LKL as [64 d][256B] ----
  #pragma unroll
  for (int d = 0; d < 8; ++d) {
    float v0 = f4get(vr[0 + (d >> 2)], d & 3);
    float v1 = f4get(vr[2 + (d >> 2)], d & 3);
    float v2 = f4get(vr[4 + (d >> 2)], d & 3);
    float v3 = f4get(vr[6 + (d >> 2)], d & 3);
    unsigned a = vhp[2 * d], bb = vhp[2 * d + 1];
    unsigned la = cvtpk(v0 - pk0f(a), v1 - pk1f(a));
    unsigned lb = cvtpk(v2 - pk0f(bb), v3 - pk1f(bb));
    *(uint2*)(smem + LKL + SWZ256(vd0 + d, vt0 * 2)) = make_uint2(la, lb);
  }
  __syncthreads();  // s4: P + V^T staged

  // ---- PV: A = P rows (q = 16w+lr), B = V^T hi + lo ----
  bf16x8 pa[4];
  #pragma unroll
  for (int ks = 0; ks < 4; ++ks)
    pa[ks] = *(const bf16x8*)(smem + LKH + SWZ256(16 * wid + lr, lg * 16 + ks * 64));
  f32x4 o[4];
  #pragma unroll
  for (int t = 0; t < 4; ++t) o[t] = (f32x4){0.f, 0.f, 0.f, 0.f};
  #pragma unroll
  for (int t = 0; t < 4; ++t) {
    #pragma unroll
    for (int ks = 0; ks < 4; ++ks) {
      bf16x8 bvh = *(const bf16x8*)(smem + LVH + SWZ256(16 * t + lr, lg * 16 + ks * 64));
      o[t] = mfma16(pa[ks], bvh, o[t]);
      bf16x8 bvl = *(const bf16x8*)(smem + LKL + SWZ256(16 * t + lr, lg * 16 + ks * 64));
      o[t] = mfma16(pa[ks], bvl, o[t]);
    }
  }

  // ---- normalize by l of output row q' = 16w + 4lg + rr ----
  float rl[4];
  #pragma unroll
  for (int rr = 0; rr < 4; ++rr) rl[rr] = 1.0f / __shfl(ll, 4 * lg + rr);
  #pragma unroll
  for (int t = 0; t < 4; ++t)
    #pragma unroll
    for (int rr = 0; rr < 4; ++rr) o[t][rr] *= rl[rr];

  __syncthreads();  // s5: all PV LDS reads done
  // ---- O stage fp32 over LVH [64 q][256B], then coalesced scatter ----
  #pragma unroll
  for (int t = 0; t < 4; ++t)
    #pragma unroll
    for (int rr = 0; rr < 4; ++rr)
      *(float*)(smem + LVH + SWZ256(16 * wid + 4 * lg + rr, (16 * t + lr) * 4)) = o[t][rr];
  __syncthreads();  // s6
  {
    const int row = tid >> 2, cq = tid & 3;
    const int tt = sIdx[row];
    size_t gb = (ps + (size_t)tt) * 64 + cq * 16;
    #pragma unroll
    for (int cc = 0; cc < 4; ++cc)
      *(float4*)&o_ws[gb + cc * 4] =
          *(const float4*)(smem + LVH + SWZ256(row, cq * 64 + cc * 16));
  }
}

// ---------------------------------------------------------------------------
// K4: combine hashes. grid (BH*T*64/256), block 256.
// ---------------------------------------------------------------------------
__global__ __launch_bounds__(256) void k_combine(const float* __restrict__ o_ws,
                                                 const float* __restrict__ lse_ws,
                                                 float* __restrict__ out) {
  const int gid = blockIdx.x * 256 + threadIdx.x;
  const int d = gid & 63;
  const int row = gid >> 6;
  const int bh = row >> 12;
  const int t = row & (T - 1);

  float ls[8];
  float mm = -INFINITY;
  #pragma unroll
  for (int r = 0; r < 8; ++r) {
    ls[r] = lse_ws[((size_t)r * BHN + bh) * T + t];
    mm = fmaxf(mm, ls[r]);
  }
  float sum = 0.f;
  #pragma unroll
  for (int r = 0; r < 8; ++r) { ls[r] = __expf(ls[r] - mm); sum += ls[r]; }
  float rcp = 1.0f / sum;

  float acc = 0.f;
  #pragma unroll
  for (int r = 0; r < 8; ++r)
    acc += ls[r] * o_ws[(((size_t)r * BHN + bh) * T + t) * 64 + d];
  acc *= rcp;

  const int b = bh >> 3, hh = bh & 7;
  out[(((size_t)b * T + t) * 8 + hh) * 64 + d] = acc;
}

// ---------------------------------------------------------------------------
extern "C" void kernel_launch(void* const* d_in, const int* in_sizes, int n_in,
                              void* d_out, int out_size, void* d_ws, size_t ws_size,
                              hipStream_t stream) {
  const float* qk  = (const float*)d_in[0];
  const float* v   = (const float*)d_in[1];
  const float* rot = (const float*)d_in[2];
  float* out = (float*)d_out;

  // workspace layout (bytes) — total 145,752,064 (within proven budget)
  char* ws = (char*)d_ws;
  float* o_ws           = (float*)(ws);                      // 134217728
  int* perm             = (int*)(ws + 134217728);            // 8388608
  unsigned char* bkts   = (unsigned char*)(ws + 142606336);  // 524288
  float* lse_ws         = (float*)(ws + 143130624);          // 2097152
  float* norm025        = (float*)(ws + 145227776);          // 262144
  float* inv_norm       = (float*)(ws + 145489920);          // 262144

  k_bucket<<<dim3(T / 64, BHN, NH), 64, 0, stream>>>(qk, rot, bkts, inv_norm, norm025);
  k_sort<<<dim3(NH * BHN), 1024, 0, stream>>>(bkts, perm);
  k_attn3<<<dim3(NB, BHN, NH), 256, 0, stream>>>(qk, v, perm, inv_norm, norm025,
                                                 o_ws, lse_ws);
  k_combine<<<dim3((BHN * T * 64) / 256), 256, 0, stream>>>(o_ws, lse_ws, out);
}

// Round 5
// 204.425 us; speedup vs baseline: 1.3179x; 1.0697x over previous
//
#include <hip/hip_runtime.h>
#include <hip/hip_bf16.h>
#include <math.h>

#define T 4096
#define NH 8
#define BHN 16
#define NB 64   // buckets per sequence
#define BS 64   // bucket size

using bf16x8 = __attribute__((ext_vector_type(8))) short;
using f32x4  = __attribute__((ext_vector_type(4))) float;

__device__ __forceinline__ f32x4 mfma16(bf16x8 a, bf16x8 b, f32x4 c) {
  return __builtin_amdgcn_mfma_f32_16x16x32_bf16(a, b, c, 0, 0, 0);
}

// packed fp32x2 -> bf16x2 (RNE), elem0 in low half
__device__ __forceinline__ unsigned cvtpk(float a, float b) {
  __hip_bfloat162 p = __float22bfloat162_rn(make_float2(a, b));
  unsigned u; __builtin_memcpy(&u, &p, 4); return u;
}
__device__ __forceinline__ float pk0f(unsigned h) { return __uint_as_float(h << 16); }
__device__ __forceinline__ float pk1f(unsigned h) { return __uint_as_float(h & 0xffff0000u); }
__device__ __forceinline__ float f4get(const float4& v, int i) {
  return i == 0 ? v.x : i == 1 ? v.y : i == 2 ? v.z : v.w;
}

// byte-offset swizzles: rows of 128B / 256B, XOR low row bits into 16B-slot bits
#define SWZ128(row, inb) ((((row)) << 7) + ((inb) ^ ((((row)) & 7) << 4)))
#define SWZ256(row, inb) ((((row)) << 8) + ((inb) ^ ((((row)) & 7) << 4)))

// ---------------------------------------------------------------------------
// K1: LSH buckets, one hash per block-z; z==0 also writes inv_norm + norm025.
// grid (T/64, BH, NH), block 64.
// ---------------------------------------------------------------------------
__global__ __launch_bounds__(64) void k_bucket(const float* __restrict__ qk,
                                               const float* __restrict__ rot,
                                               unsigned char* __restrict__ buckets,
                                               float* __restrict__ inv_norm,
                                               float* __restrict__ norm025) {
  __shared__ float sQ[64][65];
  const int tid = threadIdx.x;
  const int t0 = blockIdx.x * 64;
  const int bh = blockIdx.y;
  const int r  = blockIdx.z;
  const int b = bh >> 3, hh = bh & 7;
  const size_t gbase = (size_t)b * ((size_t)T * 512) + (size_t)hh * 64;

  // vectorized stage: 4 rows per iter, 16 lanes x float4 per row
  #pragma unroll
  for (int i = 0; i < 16; ++i) {
    int rr = i * 4 + (tid >> 4);
    int cc = (tid & 15) * 4;
    float4 x = *(const float4*)&qk[gbase + (size_t)(t0 + rr) * 512 + cc];
    sQ[rr][cc] = x.x; sQ[rr][cc + 1] = x.y; sQ[rr][cc + 2] = x.z; sQ[rr][cc + 3] = x.w;
  }
  __syncthreads();

  const int t = t0 + tid;
  if (r == 0) {
    float ss = 0.f;
    #pragma unroll
    for (int f = 0; f < 64; ++f) { float q = sQ[tid][f]; ss += q * q; }
    float in = rsqrtf(ss);
    inv_norm[(size_t)bh * T + t] = in;
    norm025[(size_t)bh * T + t] = 0.125f * ss * in;  // 0.125*||qk||
  }

  float acc[32];
  #pragma unroll
  for (int i = 0; i < 32; ++i) acc[i] = 0.f;
  for (int f = 0; f < 64; ++f) {
    float qv = sQ[tid][f];
    const float* rp = rot + (size_t)f * (NH * 32) + r * 32;
    #pragma unroll
    for (int i = 0; i < 32; ++i) acc[i] += qv * rp[i];
  }
  float maxv = -INFINITY, minv = INFINITY;
  int amax = 0, amin = 0;
  #pragma unroll
  for (int i = 0; i < 32; ++i) {
    if (acc[i] > maxv) { maxv = acc[i]; amax = i; }
    if (acc[i] < minv) { minv = acc[i]; amin = i; }
  }
  int bucket = (maxv >= -minv) ? amax : 32 + amin;
  buckets[((size_t)r * BHN + bh) * T + t] = (unsigned char)bucket;
}

// ---------------------------------------------------------------------------
// K2: stable counting argsort per (hash, bh) segment. grid (NH*BH), block 1024.
// ---------------------------------------------------------------------------
__global__ __launch_bounds__(1024) void k_sort(const unsigned char* __restrict__ buckets,
                                               int* __restrict__ perm) {
  __shared__ unsigned short bkt[T];
  __shared__ unsigned short rnk[T];
  __shared__ unsigned int cnt[64 * 64];
  __shared__ unsigned int bbase[64];
  __shared__ unsigned int btot[64];

  const int tid = threadIdx.x;
  const int seg = blockIdx.x;
  const unsigned char* bin = buckets + (size_t)seg * T;

  for (int idx = tid; idx < T; idx += 1024) bkt[idx] = bin[idx];
  __syncthreads();

  const int wave = tid >> 6, lane = tid & 63;
  const unsigned long long lt = (1ull << lane) - 1ull;
  for (int cc = 0; cc < 4; ++cc) {
    int chunk = wave * 4 + cc;
    int e = bkt[chunk * 64 + lane];
    for (int bb = 0; bb < 64; ++bb) {
      unsigned long long m = __ballot(e == bb);
      if (lane == bb) cnt[bb * 64 + chunk] = (unsigned int)__popcll(m);
      if (e == bb) rnk[chunk * 64 + lane] = (unsigned short)__popcll(m & lt);
    }
  }
  __syncthreads();
  if (tid < 64) {
    unsigned int run = 0;
    for (int c = 0; c < 64; ++c) {
      unsigned int v = cnt[tid * 64 + c];
      cnt[tid * 64 + c] = run;
      run += v;
    }
    btot[tid] = run;
  }
  __syncthreads();
  if (tid == 0) {
    unsigned int run = 0;
    for (int bb = 0; bb < 64; ++bb) { bbase[bb] = run; run += btot[bb]; }
  }
  __syncthreads();
  for (int idx = tid; idx < T; idx += 1024) {
    int e = bkt[idx];
    int c = idx >> 6;
    int pos = (int)(bbase[e] + cnt[e * 64 + c] + rnk[idx]);
    perm[(size_t)seg * T + pos] = idx;
  }
}

// ---------------------------------------------------------------------------
// K3: per-bucket attention. Q==K trick; S = Khi . (Qhi+Qlo) (2 chains);
// PV 2-term bf16 with V^T chunked over kv (2 x 64) to shrink LDS to 33 KB
// (4 blocks/CU). grid (NB, BH, NH), block 256 (4 waves).
// ---------------------------------------------------------------------------
__global__ __launch_bounds__(256, 4) void k_attn5(
    const float* __restrict__ qk, const float* __restrict__ vglob,
    const int* __restrict__ perm, const float* __restrict__ inv_norm,
    const float* __restrict__ norm025,
    float* __restrict__ o_ws, float* __restrict__ lse_ws) {
  __shared__ __align__(16) char smem[33280];
  constexpr int LKH = 0;        // ph1: Khat hi [128][128B] SWZ128; ph2: P [64][256B] SWZ256
  constexpr int LKL = 16384;    // ph1: Khat lo (q rows) [64][128B]; ph2: V^T lo [64][128B]
  constexpr int LVH = 24576;    // V^T hi chunk [64][128B] SWZ128
  constexpr int LIDX = 32768;   // 128 ints
  int* sIdx = (int*)(smem + LIDX);

  const int tid = threadIdx.x;
  const int n = blockIdx.x, bh = blockIdx.y, r = blockIdx.z;
  const int b = bh >> 3, hh = bh & 7;
  const size_t gbase = (size_t)b * ((size_t)T * 512) + (size_t)hh * 64;
  const size_t rowbase = (size_t)bh * T;
  const size_t ps = ((size_t)r * BHN + bh) * T;

  if (tid < 128) {
    int src = (tid < 64) ? (n * 64 + tid) : (((n + 63) & 63) * 64 + (tid - 64));
    sIdx[tid] = perm[ps + src];
  }
  __syncthreads();  // s1

  // ---- V chunk 0 gather (kv rows 0..63); in flight across K staging ----
  const int vj0 = (tid & 15) * 4, vd0 = (tid >> 4) * 4;
  float4 vc[4];
  #pragma unroll
  for (int j = 0; j < 4; ++j)
    vc[j] = *(const float4*)&vglob[gbase + (size_t)sIdx[vj0 + j] * 512 + vd0];

  // ---- K staging: hi for all 128 rows; lo only for q rows 0..63 ----
  #pragma unroll
  for (int it = 0; it < 4; ++it) {
    int idx = it * 256 + tid;
    int row = idx >> 3, u = idx & 7;
    int tok = sIdx[row];
    float inr = inv_norm[rowbase + tok];
    const float* src = &qk[gbase + (size_t)tok * 512 + u * 8];
    float4 x0 = *(const float4*)src, x1 = *(const float4*)(src + 4);
    x0.x *= inr; x0.y *= inr; x0.z *= inr; x0.w *= inr;
    x1.x *= inr; x1.y *= inr; x1.z *= inr; x1.w *= inr;
    unsigned h0 = cvtpk(x0.x, x0.y), h1 = cvtpk(x0.z, x0.w);
    unsigned h2 = cvtpk(x1.x, x1.y), h3 = cvtpk(x1.z, x1.w);
    *(uint4*)(smem + LKH + SWZ128(row, u * 16)) = (uint4){h0, h1, h2, h3};
    if (it < 2) {  // rows 0..63
      unsigned l0 = cvtpk(x0.x - pk0f(h0), x0.y - pk1f(h0));
      unsigned l1 = cvtpk(x0.z - pk0f(h1), x0.w - pk1f(h1));
      unsigned l2 = cvtpk(x1.x - pk0f(h2), x1.y - pk1f(h2));
      unsigned l3 = cvtpk(x1.z - pk0f(h3), x1.w - pk1f(h3));
      *(uint4*)(smem + LKL + SWZ128(row, u * 16)) = (uint4){l0, l1, l2, l3};
    }
  }
  __syncthreads();  // s2

  const int wid = tid >> 6, lane = tid & 63;
  const int lr = lane & 15, lg = lane >> 4;
  const int qtok = sIdx[16 * wid + lr];
  const float scale = norm025[rowbase + qtok];

  // B frags = own q row (hi + lo), held in regs
  bf16x8 bqh[2], bql[2];
  #pragma unroll
  for (int ks = 0; ks < 2; ++ks) {
    bqh[ks] = *(const bf16x8*)(smem + LKH + SWZ128(16 * wid + lr, lg * 16 + ks * 64));
    bql[ks] = *(const bf16x8*)(smem + LKL + SWZ128(16 * wid + lr, lg * 16 + ks * 64));
  }

  // ---- QK (A = K hi only): 32 MFMA; V^T hi chunk0 write hidden under it ----
  f32x4 c[8];
  #pragma unroll
  for (int t = 0; t < 8; ++t) c[t] = (f32x4){0.f, 0.f, 0.f, 0.f};
  #pragma unroll
  for (int t = 0; t < 8; ++t) {
    #pragma unroll
    for (int ks = 0; ks < 2; ++ks) {
      bf16x8 ah = *(const bf16x8*)(smem + LKH + SWZ128(16 * t + lr, lg * 16 + ks * 64));
      c[t] = mfma16(ah, bqh[ks], c[t]);
      c[t] = mfma16(ah, bql[ks], c[t]);
    }
  }
  // V^T hi (chunk 0) -> LVH (fresh region, no barrier needed)
  unsigned vhp[8];
  #pragma unroll
  for (int dd = 0; dd < 4; ++dd) {
    unsigned a = cvtpk(f4get(vc[0], dd), f4get(vc[1], dd));
    unsigned bb = cvtpk(f4get(vc[2], dd), f4get(vc[3], dd));
    vhp[2 * dd] = a; vhp[2 * dd + 1] = bb;
    *(uint2*)(smem + LVH + SWZ128(vd0 + dd, vj0 * 2)) = make_uint2(a, bb);
  }

  // ---- self-mask: position diagonal (kv row == q row, rows 0..63) ----
  #pragma unroll
  for (int t = 0; t < 4; ++t) {
    #pragma unroll
    for (int rr = 0; rr < 4; ++rr)
      if (16 * t + 4 * lg + rr == 16 * wid + lr) c[t][rr] = -1e30f;
  }

  // ---- softmax (q fixed per lane; reduce lanes xor16/32) ----
  float mm = -1e30f;
  #pragma unroll
  for (int t = 0; t < 8; ++t)
    mm = fmaxf(mm, fmaxf(fmaxf(c[t][0], c[t][1]), fmaxf(c[t][2], c[t][3])));
  mm = fmaxf(mm, __shfl_xor(mm, 16));
  mm = fmaxf(mm, __shfl_xor(mm, 32));
  const float sl2e = scale * 1.4426950408889634f;
  float ll = 0.f;
  #pragma unroll
  for (int t = 0; t < 8; ++t) {
    #pragma unroll
    for (int rr = 0; rr < 4; ++rr) {
      float e = exp2f((c[t][rr] - mm) * sl2e);
      c[t][rr] = e;
      ll += e;
    }
  }
  ll += __shfl_xor(ll, 16);
  ll += __shfl_xor(ll, 32);
  if (lg == 0) lse_ws[ps + qtok] = scale * mm + __logf(ll);

  __syncthreads();  // s3: all LKH/LKL reads done

  // ---- V chunk 1 gather issue (latency hidden under P-write + PV0) ----
  float4 vc1[4];
  #pragma unroll
  for (int j = 0; j < 4; ++j)
    vc1[j] = *(const float4*)&vglob[gbase + (size_t)sIdx[64 + vj0 + j] * 512 + vd0];

  // ---- P (unnormalized bf16) over LKH as [64 q][256B] ----
  {
    const int prow = 16 * wid + lr;
    #pragma unroll
    for (int t = 0; t < 8; ++t) {
      unsigned u01 = cvtpk(c[t][0], c[t][1]);
      unsigned u23 = cvtpk(c[t][2], c[t][3]);
      *(uint2*)(smem + LKH + SWZ256(prow, 32 * t + 8 * lg)) = make_uint2(u01, u23);
    }
  }
  // ---- V^T lo (chunk 0) over LKL ----
  #pragma unroll
  for (int dd = 0; dd < 4; ++dd) {
    unsigned a = vhp[2 * dd], bb = vhp[2 * dd + 1];
    unsigned la = cvtpk(f4get(vc[0], dd) - pk0f(a), f4get(vc[1], dd) - pk1f(a));
    unsigned lb = cvtpk(f4get(vc[2], dd) - pk0f(bb), f4get(vc[3], dd) - pk1f(bb));
    *(uint2*)(smem + LKL + SWZ128(vd0 + dd, vj0 * 2)) = make_uint2(la, lb);
  }
  __syncthreads();  // s4: P + V^T chunk0 staged

  // ---- PV chunk 0 (kv 0..63) ----
  f32x4 o[4];
  #pragma unroll
  for (int t = 0; t < 4; ++t) o[t] = (f32x4){0.f, 0.f, 0.f, 0.f};
  {
    bf16x8 pa[2];
    #pragma unroll
    for (int ks = 0; ks < 2; ++ks)
      pa[ks] = *(const bf16x8*)(smem + LKH + SWZ256(16 * wid + lr, ks * 64 + lg * 16));
    #pragma unroll
    for (int td = 0; td < 4; ++td) {
      #pragma unroll
      for (int ks = 0; ks < 2; ++ks) {
        bf16x8 bvh = *(const bf16x8*)(smem + LVH + SWZ128(16 * td + lr, lg * 16 + ks * 64));
        o[td] = mfma16(pa[ks], bvh, o[td]);
        bf16x8 bvl = *(const bf16x8*)(smem + LKL + SWZ128(16 * td + lr, lg * 16 + ks * 64));
        o[td] = mfma16(pa[ks], bvl, o[td]);
      }
    }
  }
  __syncthreads();  // s5: chunk0 V^T reads done

  // ---- V^T chunk 1 (hi -> LVH, lo -> LKL) ----
  #pragma unroll
  for (int dd = 0; dd < 4; ++dd) {
    unsigned a = cvtpk(f4get(vc1[0], dd), f4get(vc1[1], dd));
    unsigned bb = cvtpk(f4get(vc1[2], dd), f4get(vc1[3], dd));
    unsigned la = cvtpk(f4get(vc1[0], dd) - pk0f(a), f4get(vc1[1], dd) - pk1f(a));
    unsigned lb = cvtpk(f4get(vc1[2], dd) - pk0f(bb), f4get(vc1[3], dd) - pk1f(bb));
    *(uint2*)(smem + LVH + SWZ128(vd0 + dd, vj0 * 2)) = make_uint2(a, bb);
    *(uint2*)(smem + LKL + SWZ128(vd0 + dd, vj0 * 2)) = make_uint2(la, lb);
  }
  __syncthreads();  // s6: chunk1 staged

  // ---- PV chunk 1 (kv 64..127) ----
  {
    bf16x8 pa[2];
    #pragma unroll
    for (int ks = 0; ks < 2; ++ks)
      pa[ks] = *(const bf16x8*)(smem + LKH + SWZ256(16 * wid + lr, 128 + ks * 64 + lg * 16));
    #pragma unroll
    for (int td = 0; td < 4; ++td) {
      #pragma unroll
      for (int ks = 0; ks < 2; ++ks) {
        bf16x8 bvh = *(const bf16x8*)(smem + LVH + SWZ128(16 * td + lr, lg * 16 + ks * 64));
        o[td] = mfma16(pa[ks], bvh, o[td]);
        bf16x8 bvl = *(const bf16x8*)(smem + LKL + SWZ128(16 * td + lr, lg * 16 + ks * 64));
        o[td] = mfma16(pa[ks], bvl, o[td]);
      }
    }
  }

  // ---- normalize + direct coalesced-ish O stores (no LDS round trip) ----
  float rl[4];
  int otok[4];
  #pragma unroll
  for (int rr = 0; rr < 4; ++rr) {
    rl[rr] = 1.0f / __shfl(ll, 4 * lg + rr);
    otok[rr] = sIdx[16 * wid + 4 * lg + rr];
  }
  #pragma unroll
  for (int rr = 0; rr < 4; ++rr) {
    size_t gb = (ps + (size_t)otok[rr]) * 64 + lr;
    #pragma unroll
    for (int td = 0; td < 4; ++td)
      o_ws[gb + 16 * td] = o[td][rr] * rl[rr];
  }
}

// ---------------------------------------------------------------------------
// K4: combine hashes (float4 per thread). grid (BH*T*16/256), block 256.
// ---------------------------------------------------------------------------
__global__ __launch_bounds__(256) void k_combine(const float* __restrict__ o_ws,
                                                 const float* __restrict__ lse_ws,
                                                 float* __restrict__ out) {
  const int gid = blockIdx.x * 256 + threadIdx.x;
  const int d4 = (gid & 15) * 4;
  const int row = gid >> 4;   // bh*T + t
  const int bh = row >> 12;
  const int t = row & (T - 1);

  float ls[8];
  float mm = -INFINITY;
  #pragma unroll
  for (int r = 0; r < 8; ++r) {
    ls[r] = lse_ws[((size_t)r * BHN + bh) * T + t];
    mm = fmaxf(mm, ls[r]);
  }
  float sum = 0.f;
  #pragma unroll
  for (int r = 0; r < 8; ++r) { ls[r] = __expf(ls[r] - mm); sum += ls[r]; }
  float rcp = 1.0f / sum;

  float4 acc = make_float4(0.f, 0.f, 0.f, 0.f);
  #pragma unroll
  for (int r = 0; r < 8; ++r) {
    float4 ov = *(const float4*)&o_ws[(((size_t)r * BHN + bh) * T + t) * 64 + d4];
    acc.x += ls[r] * ov.x; acc.y += ls[r] * ov.y;
    acc.z += ls[r] * ov.z; acc.w += ls[r] * ov.w;
  }
  acc.x *= rcp; acc.y *= rcp; acc.z *= rcp; acc.w *= rcp;

  const int b = bh >> 3, hh = bh & 7;
  *(float4*)&out[(((size_t)b * T + t) * 8 + hh) * 64 + d4] = acc;
}

// ---------------------------------------------------------------------------
extern "C" void kernel_launch(void* const* d_in, const int* in_sizes, int n_in,
                              void* d_out, int out_size, void* d_ws, size_t ws_size,
                              hipStream_t stream) {
  const float* qk  = (const float*)d_in[0];
  const float* v   = (const float*)d_in[1];
  const float* rot = (const float*)d_in[2];
  float* out = (float*)d_out;

  // workspace layout (bytes) — total 145,752,064 (within proven budget)
  char* ws = (char*)d_ws;
  float* o_ws           = (float*)(ws);                      // 134217728
  int* perm             = (int*)(ws + 134217728);            // 8388608
  unsigned char* bkts   = (unsigned char*)(ws + 142606336);  // 524288
  float* lse_ws         = (float*)(ws + 143130624);          // 2097152
  float* norm025        = (float*)(ws + 145227776);          // 262144
  float* inv_norm       = (float*)(ws + 145489920);          // 262144

  k_bucket<<<dim3(T / 64, BHN, NH), 64, 0, stream>>>(qk, rot, bkts, inv_norm, norm025);
  k_sort<<<dim3(NH * BHN), 1024, 0, stream>>>(bkts, perm);
  k_attn5<<<dim3(NB, BHN, NH), 256, 0, stream>>>(qk, v, perm, inv_norm, norm025,
                                                 o_ws, lse_ws);
  k_combine<<<dim3((BHN * T * 16) / 256), 256, 0, stream>>>(o_ws, lse_ws, out);
}

// Round 6
// 177.338 us; speedup vs baseline: 1.5192x; 1.1527x over previous
//
#include <hip/hip_runtime.h>
#include <hip/hip_bf16.h>
#include <hip/hip_fp16.h>
#include <math.h>

#define T 4096
#define NH 8
#define BHN 16
#define NB 64   // buckets per sequence
#define BS 64   // bucket size

using bf16x8 = __attribute__((ext_vector_type(8))) short;
using f32x4  = __attribute__((ext_vector_type(4))) float;

__device__ __forceinline__ f32x4 mfma16(bf16x8 a, bf16x8 b, f32x4 c) {
  return __builtin_amdgcn_mfma_f32_16x16x32_bf16(a, b, c, 0, 0, 0);
}

// packed fp32x2 -> bf16x2 (RNE), elem0 in low half
__device__ __forceinline__ unsigned cvtpk(float a, float b) {
  __hip_bfloat162 p = __float22bfloat162_rn(make_float2(a, b));
  unsigned u; __builtin_memcpy(&u, &p, 4); return u;
}
__device__ __forceinline__ float pk0f(unsigned h) { return __uint_as_float(h << 16); }
__device__ __forceinline__ float pk1f(unsigned h) { return __uint_as_float(h & 0xffff0000u); }
__device__ __forceinline__ float f4get(const float4& v, int i) {
  return i == 0 ? v.x : i == 1 ? v.y : i == 2 ? v.z : v.w;
}
__device__ __forceinline__ unsigned u4get(const uint4& v, int i) {
  return i == 0 ? v.x : i == 1 ? v.y : i == 2 ? v.z : v.w;
}

// async global->LDS, 16B per lane, linear LDS dest (wave-uniform base + lane*16)
__device__ __forceinline__ void async_load16(const void* src, void* dst_lds) {
  __builtin_amdgcn_global_load_lds(
      (const __attribute__((address_space(1))) unsigned int*)src,
      (__attribute__((address_space(3))) unsigned int*)dst_lds, 16, 0, 0);
}

// byte-offset swizzles: rows of 128B / 256B, XOR low row bits into 16B-slot bits
#define SWZ128(row, inb) ((((row)) << 7) + ((inb) ^ ((((row)) & 7) << 4)))
#define SWZ256(row, inb) ((((row)) << 8) + ((inb) ^ ((((row)) & 7) << 4)))

// ---------------------------------------------------------------------------
// K_prep: per (bh, token): k_hat hi/lo bf16, v hi/lo bf16, norm025.
// grid (T/64, BH), block 256 (4 threads per token, 16 elems each).
// ---------------------------------------------------------------------------
__global__ __launch_bounds__(256) void k_prep(const float* __restrict__ qk,
                                              const float* __restrict__ v,
                                              unsigned short* __restrict__ khi,
                                              unsigned short* __restrict__ klo,
                                              unsigned short* __restrict__ vhi,
                                              unsigned short* __restrict__ vlo,
                                              float* __restrict__ norm025) {
  const int tid = threadIdx.x;
  const int tok = blockIdx.x * 64 + (tid >> 2);
  const int bh = blockIdx.y;
  const int b = bh >> 3, hh = bh & 7;
  const int q4 = tid & 3;
  const size_t g = ((size_t)b * T + tok) * 512 + hh * 64 + q4 * 16;

  float4 x[4], y[4];
  #pragma unroll
  for (int k = 0; k < 4; ++k) {
    x[k] = *(const float4*)&qk[g + k * 4];
    y[k] = *(const float4*)&v[g + k * 4];
  }
  float ss = 0.f;
  #pragma unroll
  for (int k = 0; k < 4; ++k)
    ss += x[k].x * x[k].x + x[k].y * x[k].y + x[k].z * x[k].z + x[k].w * x[k].w;
  ss += __shfl_xor(ss, 1);
  ss += __shfl_xor(ss, 2);
  const float invn = rsqrtf(ss);

  const size_t ob = ((size_t)bh * T + tok) * 64 + q4 * 16;
  unsigned kh[8], kl[8], vh[8], vl[8];
  #pragma unroll
  for (int k = 0; k < 4; ++k) {
    #pragma unroll
    for (int p = 0; p < 2; ++p) {
      float a0 = f4get(x[k], 2 * p) * invn, a1 = f4get(x[k], 2 * p + 1) * invn;
      unsigned h = cvtpk(a0, a1);
      unsigned l = cvtpk(a0 - pk0f(h), a1 - pk1f(h));
      kh[k * 2 + p] = h; kl[k * 2 + p] = l;
      float b0 = f4get(y[k], 2 * p), b1 = f4get(y[k], 2 * p + 1);
      unsigned hv = cvtpk(b0, b1);
      unsigned lv = cvtpk(b0 - pk0f(hv), b1 - pk1f(hv));
      vh[k * 2 + p] = hv; vl[k * 2 + p] = lv;
    }
  }
  *(uint4*)&khi[ob]     = (uint4){kh[0], kh[1], kh[2], kh[3]};
  *(uint4*)&khi[ob + 8] = (uint4){kh[4], kh[5], kh[6], kh[7]};
  *(uint4*)&klo[ob]     = (uint4){kl[0], kl[1], kl[2], kl[3]};
  *(uint4*)&klo[ob + 8] = (uint4){kl[4], kl[5], kl[6], kl[7]};
  *(uint4*)&vhi[ob]     = (uint4){vh[0], vh[1], vh[2], vh[3]};
  *(uint4*)&vhi[ob + 8] = (uint4){vh[4], vh[5], vh[6], vh[7]};
  *(uint4*)&vlo[ob]     = (uint4){vl[0], vl[1], vl[2], vl[3]};
  *(uint4*)&vlo[ob + 8] = (uint4){vl[4], vl[5], vl[6], vl[7]};
  if (q4 == 0) norm025[(size_t)bh * T + tok] = 0.125f * ss * invn;
}

// ---------------------------------------------------------------------------
// K1: LSH buckets, one hash per block-z. grid (T/64, BH, NH), block 64.
// ---------------------------------------------------------------------------
__global__ __launch_bounds__(64) void k_bucket(const float* __restrict__ qk,
                                               const float* __restrict__ rot,
                                               unsigned char* __restrict__ buckets) {
  __shared__ float sQ[64][65];
  const int tid = threadIdx.x;
  const int t0 = blockIdx.x * 64;
  const int bh = blockIdx.y;
  const int r  = blockIdx.z;
  const int b = bh >> 3, hh = bh & 7;
  const size_t gbase = (size_t)b * ((size_t)T * 512) + (size_t)hh * 64;

  #pragma unroll
  for (int i = 0; i < 16; ++i) {
    int rr = i * 4 + (tid >> 4);
    int cc = (tid & 15) * 4;
    float4 x = *(const float4*)&qk[gbase + (size_t)(t0 + rr) * 512 + cc];
    sQ[rr][cc] = x.x; sQ[rr][cc + 1] = x.y; sQ[rr][cc + 2] = x.z; sQ[rr][cc + 3] = x.w;
  }
  __syncthreads();

  const int t = t0 + tid;
  float acc[32];
  #pragma unroll
  for (int i = 0; i < 32; ++i) acc[i] = 0.f;
  for (int f = 0; f < 64; ++f) {
    float qv = sQ[tid][f];
    const float* rp = rot + (size_t)f * (NH * 32) + r * 32;
    #pragma unroll
    for (int i = 0; i < 32; ++i) acc[i] += qv * rp[i];
  }
  float maxv = -INFINITY, minv = INFINITY;
  int amax = 0, amin = 0;
  #pragma unroll
  for (int i = 0; i < 32; ++i) {
    if (acc[i] > maxv) { maxv = acc[i]; amax = i; }
    if (acc[i] < minv) { minv = acc[i]; amin = i; }
  }
  int bucket = (maxv >= -minv) ? amax : 32 + amin;
  buckets[((size_t)r * BHN + bh) * T + t] = (unsigned char)bucket;
}

// ---------------------------------------------------------------------------
// K2: stable counting argsort per (hash, bh) segment. grid (NH*BH), block 1024.
// ---------------------------------------------------------------------------
__global__ __launch_bounds__(1024) void k_sort(const unsigned char* __restrict__ buckets,
                                               int* __restrict__ perm) {
  __shared__ unsigned short bkt[T];
  __shared__ unsigned short rnk[T];
  __shared__ unsigned int cnt[64 * 64];
  __shared__ unsigned int bbase[64];
  __shared__ unsigned int btot[64];

  const int tid = threadIdx.x;
  const int seg = blockIdx.x;
  const unsigned char* bin = buckets + (size_t)seg * T;

  for (int idx = tid; idx < T; idx += 1024) bkt[idx] = bin[idx];
  __syncthreads();

  const int wave = tid >> 6, lane = tid & 63;
  const unsigned long long lt = (1ull << lane) - 1ull;
  for (int cc = 0; cc < 4; ++cc) {
    int chunk = wave * 4 + cc;
    int e = bkt[chunk * 64 + lane];
    for (int bb = 0; bb < 64; ++bb) {
      unsigned long long m = __ballot(e == bb);
      if (lane == bb) cnt[bb * 64 + chunk] = (unsigned int)__popcll(m);
      if (e == bb) rnk[chunk * 64 + lane] = (unsigned short)__popcll(m & lt);
    }
  }
  __syncthreads();
  if (tid < 64) {
    unsigned int run = 0;
    for (int c = 0; c < 64; ++c) {
      unsigned int v = cnt[tid * 64 + c];
      cnt[tid * 64 + c] = run;
      run += v;
    }
    btot[tid] = run;
  }
  __syncthreads();
  if (tid == 0) {
    unsigned int run = 0;
    for (int bb = 0; bb < 64; ++bb) { bbase[bb] = run; run += btot[bb]; }
  }
  __syncthreads();
  for (int idx = tid; idx < T; idx += 1024) {
    int e = bkt[idx];
    int c = idx >> 6;
    int pos = (int)(bbase[e] + cnt[e * 64 + c] + rnk[idx]);
    perm[(size_t)seg * T + pos] = idx;
  }
}

// ---------------------------------------------------------------------------
// K3: per-bucket attention on preconverted bf16 inputs. K staged via
// global_load_lds (inverse-swizzled source); V gathered bf16 + reg transpose;
// O stored fp16. LDS exactly 32KB -> 5 blocks/CU. grid 8192 linear (XCD-
// swizzled), block 256 (4 waves).
// ---------------------------------------------------------------------------
__global__ __launch_bounds__(256, 5) void k_attn6(
    const unsigned short* __restrict__ khi, const unsigned short* __restrict__ klo,
    const unsigned short* __restrict__ vhi, const unsigned short* __restrict__ vlo,
    const int* __restrict__ perm, const float* __restrict__ norm025,
    __half* __restrict__ o_ws, float* __restrict__ lse_ws) {
  __shared__ __align__(16) char smem[32768];
  constexpr int LKH  = 0;       // ph1: Khat hi [128 kv][128B] SWZ128
  constexpr int LKL  = 16384;   // ph1: Khat lo (q rows) [64][128B]
  constexpr int LP   = 0;       // ph2: P [64 q][256B] SWZ256 (over LKH)
  constexpr int LVTL = 16384;   // ph2: V^T lo chunk [64 d][128B] (over LKL)
  constexpr int LVTH = 24576;   // V^T hi chunk [64 d][128B] (fresh region)

  const int tid = threadIdx.x;
  // XCD-aware bijective swizzle (8192 % 8 == 0): XCD x gets hash r = x.
  const int wg = ((int)blockIdx.x & 7) * 1024 + ((int)blockIdx.x >> 3);
  const int n = wg & 63, bh = (wg >> 6) & 15, r = wg >> 10;
  const size_t rowbase = (size_t)bh * T;
  const size_t ps = ((size_t)r * BHN + bh) * T;
  const int base_own = n * 64;
  const int base_prev = ((n + 63) & 63) * 64;

  const int wid = tid >> 6, lane = tid & 63;
  const int lr = lane & 15, lg = lane >> 4;

  // q/o token indices + scale (perm is 512B/block, L2-hot)
  const int qtok = perm[ps + base_own + 16 * wid + lr];
  const float scale = norm025[rowbase + qtok];
  int otok[4];
  #pragma unroll
  for (int rr = 0; rr < 4; ++rr)
    otok[rr] = perm[ps + base_own + 16 * wid + 4 * lg + rr];

  // ---- V chunk0 gather (kv 0..63, own bucket): 2 tokens x 8 d per thread ----
  const int vj0 = (tid & 31) * 2, vd0 = (tid >> 5) * 8;
  int vtk0[2], vtk1[2];
  vtk0[0] = perm[ps + base_own + vj0];
  vtk0[1] = perm[ps + base_own + vj0 + 1];
  vtk1[0] = perm[ps + base_prev + vj0];
  vtk1[1] = perm[ps + base_prev + vj0 + 1];
  uint4 VH0[2], VL0[2];
  #pragma unroll
  for (int j = 0; j < 2; ++j) {
    size_t vb = (rowbase + (size_t)vtk0[j]) * 64 + vd0;
    VH0[j] = *(const uint4*)&vhi[vb];
    VL0[j] = *(const uint4*)&vlo[vb];
  }

  // ---- K staging: global_load_lds, linear dest + inverse-swizzled source ----
  #pragma unroll
  for (int it = 0; it < 4; ++it) {
    int unit = it * 256 + tid;
    int row = unit >> 3, sl = unit & 7;
    int ssl = sl ^ (row & 7);
    int src = (row < 64) ? (base_own + row) : (base_prev + (row - 64));
    int tokr = perm[ps + src];
    async_load16(&khi[(rowbase + (size_t)tokr) * 64 + ssl * 8], smem + LKH + unit * 16);
  }
  #pragma unroll
  for (int it = 0; it < 2; ++it) {
    int unit = it * 256 + tid;
    int row = unit >> 3, sl = unit & 7;
    int ssl = sl ^ (row & 7);
    int tokr = perm[ps + base_own + row];
    async_load16(&klo[(rowbase + (size_t)tokr) * 64 + ssl * 8], smem + LKL + unit * 16);
  }
  __syncthreads();  // s2: K staged (drains vmcnt)

  // B frags = own q row (hi + lo), held in regs before P overlays LKH
  bf16x8 bqh[2], bql[2];
  #pragma unroll
  for (int ks = 0; ks < 2; ++ks) {
    bqh[ks] = *(const bf16x8*)(smem + LKH + SWZ128(16 * wid + lr, lg * 16 + ks * 64));
    bql[ks] = *(const bf16x8*)(smem + LKL + SWZ128(16 * wid + lr, lg * 16 + ks * 64));
  }

  // ---- QK: S^T[kv][q] = Khi . (Qhi + Qlo), 32 MFMA ----
  f32x4 c[8];
  #pragma unroll
  for (int t = 0; t < 8; ++t) c[t] = (f32x4){0.f, 0.f, 0.f, 0.f};
  #pragma unroll
  for (int t = 0; t < 8; ++t) {
    #pragma unroll
    for (int ks = 0; ks < 2; ++ks) {
      bf16x8 ah = *(const bf16x8*)(smem + LKH + SWZ128(16 * t + lr, lg * 16 + ks * 64));
      c[t] = mfma16(ah, bqh[ks], c[t]);
      c[t] = mfma16(ah, bql[ks], c[t]);
    }
  }

  // ---- V^T hi chunk0 -> LVTH (fresh region; hidden under QK) ----
  #pragma unroll
  for (int dd = 0; dd < 8; ++dd) {
    int jd = dd >> 1;
    unsigned a = u4get(VH0[0], jd), b2 = u4get(VH0[1], jd);
    unsigned w = (dd & 1) ? ((a >> 16) | (b2 & 0xffff0000u))
                          : ((a & 0xffffu) | (b2 << 16));
    *(unsigned*)(smem + LVTH + SWZ128(vd0 + dd, vj0 * 2)) = w;
  }

  // ---- self-mask: position diagonal (q row == kv row in 0..63) ----
  #pragma unroll
  for (int t = 0; t < 4; ++t) {
    #pragma unroll
    for (int rr = 0; rr < 4; ++rr)
      if (16 * t + 4 * lg + rr == 16 * wid + lr) c[t][rr] = -1e30f;
  }

  // ---- softmax (q fixed per lane; reduce lanes xor16/32) ----
  float mm = -1e30f;
  #pragma unroll
  for (int t = 0; t < 8; ++t)
    mm = fmaxf(mm, fmaxf(fmaxf(c[t][0], c[t][1]), fmaxf(c[t][2], c[t][3])));
  mm = fmaxf(mm, __shfl_xor(mm, 16));
  mm = fmaxf(mm, __shfl_xor(mm, 32));
  const float sl2e = scale * 1.4426950408889634f;
  float ll = 0.f;
  #pragma unroll
  for (int t = 0; t < 8; ++t) {
    #pragma unroll
    for (int rr = 0; rr < 4; ++rr) {
      float e = exp2f((c[t][rr] - mm) * sl2e);
      c[t][rr] = e;
      ll += e;
    }
  }
  ll += __shfl_xor(ll, 16);
  ll += __shfl_xor(ll, 32);
  if (lg == 0) lse_ws[ps + qtok] = scale * mm + __logf(ll);

  __syncthreads();  // s3: all LKH/LKL reads done

  // ---- V chunk1 gather issue (hidden under P-write + PV0) ----
  uint4 VH1[2], VL1[2];
  #pragma unroll
  for (int j = 0; j < 2; ++j) {
    size_t vb = (rowbase + (size_t)vtk1[j]) * 64 + vd0;
    VH1[j] = *(const uint4*)&vhi[vb];
    VL1[j] = *(const uint4*)&vlo[vb];
  }

  // ---- P (unnormalized bf16) over LKH as [64 q][256B] ----
  {
    const int prow = 16 * wid + lr;
    #pragma unroll
    for (int t = 0; t < 8; ++t) {
      unsigned u01 = cvtpk(c[t][0], c[t][1]);
      unsigned u23 = cvtpk(c[t][2], c[t][3]);
      *(uint2*)(smem + LP + SWZ256(prow, 32 * t + 8 * lg)) = make_uint2(u01, u23);
    }
  }
  // ---- V^T lo chunk0 over LVTL ----
  #pragma unroll
  for (int dd = 0; dd < 8; ++dd) {
    int jd = dd >> 1;
    unsigned a = u4get(VL0[0], jd), b2 = u4get(VL0[1], jd);
    unsigned w = (dd & 1) ? ((a >> 16) | (b2 & 0xffff0000u))
                          : ((a & 0xffffu) | (b2 << 16));
    *(unsigned*)(smem + LVTL + SWZ128(vd0 + dd, vj0 * 2)) = w;
  }
  __syncthreads();  // s4: P + V^T chunk0 staged

  // ---- PV chunk 0 (kv 0..63) ----
  f32x4 o[4];
  #pragma unroll
  for (int t = 0; t < 4; ++t) o[t] = (f32x4){0.f, 0.f, 0.f, 0.f};
  {
    bf16x8 pa[2];
    #pragma unroll
    for (int ks = 0; ks < 2; ++ks)
      pa[ks] = *(const bf16x8*)(smem + LP + SWZ256(16 * wid + lr, ks * 64 + lg * 16));
    #pragma unroll
    for (int td = 0; td < 4; ++td) {
      #pragma unroll
      for (int ks = 0; ks < 2; ++ks) {
        bf16x8 bvh = *(const bf16x8*)(smem + LVTH + SWZ128(16 * td + lr, lg * 16 + ks * 64));
        o[td] = mfma16(pa[ks], bvh, o[td]);
        bf16x8 bvl = *(const bf16x8*)(smem + LVTL + SWZ128(16 * td + lr, lg * 16 + ks * 64));
        o[td] = mfma16(pa[ks], bvl, o[td]);
      }
    }
  }
  __syncthreads();  // s5: chunk0 V^T reads done

  // ---- V^T chunk 1 (hi -> LVTH, lo -> LVTL) ----
  #pragma unroll
  for (int dd = 0; dd < 8; ++dd) {
    int jd = dd >> 1;
    unsigned ah = u4get(VH1[0], jd), bhh = u4get(VH1[1], jd);
    unsigned al = u4get(VL1[0], jd), bll = u4get(VL1[1], jd);
    unsigned wh = (dd & 1) ? ((ah >> 16) | (bhh & 0xffff0000u))
                           : ((ah & 0xffffu) | (bhh << 16));
    unsigned wl = (dd & 1) ? ((al >> 16) | (bll & 0xffff0000u))
                           : ((al & 0xffffu) | (bll << 16));
    *(unsigned*)(smem + LVTH + SWZ128(vd0 + dd, vj0 * 2)) = wh;
    *(unsigned*)(smem + LVTL + SWZ128(vd0 + dd, vj0 * 2)) = wl;
  }
  __syncthreads();  // s6: chunk1 staged

  // ---- PV chunk 1 (kv 64..127) ----
  {
    bf16x8 pa[2];
    #pragma unroll
    for (int ks = 0; ks < 2; ++ks)
      pa[ks] = *(const bf16x8*)(smem + LP + SWZ256(16 * wid + lr, 128 + ks * 64 + lg * 16));
    #pragma unroll
    for (int td = 0; td < 4; ++td) {
      #pragma unroll
      for (int ks = 0; ks < 2; ++ks) {
        bf16x8 bvh = *(const bf16x8*)(smem + LVTH + SWZ128(16 * td + lr, lg * 16 + ks * 64));
        o[td] = mfma16(pa[ks], bvh, o[td]);
        bf16x8 bvl = *(const bf16x8*)(smem + LVTL + SWZ128(16 * td + lr, lg * 16 + ks * 64));
        o[td] = mfma16(pa[ks], bvl, o[td]);
      }
    }
  }

  // ---- normalize + direct fp16 O stores ----
  float rl[4];
  #pragma unroll
  for (int rr = 0; rr < 4; ++rr) rl[rr] = 1.0f / __shfl(ll, 4 * lg + rr);
  #pragma unroll
  for (int rr = 0; rr < 4; ++rr) {
    size_t gb = (ps + (size_t)otok[rr]) * 64 + lr;
    #pragma unroll
    for (int td = 0; td < 4; ++td)
      o_ws[gb + 16 * td] = __float2half(o[td][rr] * rl[rr]);
  }
}

// ---------------------------------------------------------------------------
// K4: combine hashes (fp16 o_ws, 4 d per thread). grid (BH*T*16/256), blk 256.
// ---------------------------------------------------------------------------
__global__ __launch_bounds__(256) void k_combine(const __half* __restrict__ o_ws,
                                                 const float* __restrict__ lse_ws,
                                                 float* __restrict__ out) {
  const int gid = blockIdx.x * 256 + threadIdx.x;
  const int d4 = (gid & 15) * 4;
  const int row = gid >> 4;   // bh*T + t
  const int bh = row >> 12;
  const int t = row & (T - 1);

  float ls[8];
  float mm = -INFINITY;
  #pragma unroll
  for (int r = 0; r < 8; ++r) {
    ls[r] = lse_ws[((size_t)r * BHN + bh) * T + t];
    mm = fmaxf(mm, ls[r]);
  }
  float sum = 0.f;
  #pragma unroll
  for (int r = 0; r < 8; ++r) { ls[r] = __expf(ls[r] - mm); sum += ls[r]; }
  float rcp = 1.0f / sum;

  float a0 = 0.f, a1 = 0.f, a2 = 0.f, a3 = 0.f;
  #pragma unroll
  for (int r = 0; r < 8; ++r) {
    const __half* op = &o_ws[(((size_t)r * BHN + bh) * T + t) * 64 + d4];
    __half2 h01 = *(const __half2*)&op[0];
    __half2 h23 = *(const __half2*)&op[2];
    float2 f01 = __half22float2(h01);
    float2 f23 = __half22float2(h23);
    a0 += ls[r] * f01.x; a1 += ls[r] * f01.y;
    a2 += ls[r] * f23.x; a3 += ls[r] * f23.y;
  }
  const int b = bh >> 3, hh = bh & 7;
  *(float4*)&out[(((size_t)b * T + t) * 8 + hh) * 64 + d4] =
      make_float4(a0 * rcp, a1 * rcp, a2 * rcp, a3 * rcp);
}

// ---------------------------------------------------------------------------
extern "C" void kernel_launch(void* const* d_in, const int* in_sizes, int n_in,
                              void* d_out, int out_size, void* d_ws, size_t ws_size,
                              hipStream_t stream) {
  const float* qk  = (const float*)d_in[0];
  const float* v   = (const float*)d_in[1];
  const float* rot = (const float*)d_in[2];
  float* out = (float*)d_out;

  // workspace layout (bytes) — total 111,935,488 (within proven budget)
  char* ws = (char*)d_ws;
  __half* o_ws          = (__half*)(ws);                      // 67,108,864
  int* perm             = (int*)(ws + 67108864);              //  8,388,608
  unsigned char* bkts   = (unsigned char*)(ws + 75497472);    //    524,288
  float* lse_ws         = (float*)(ws + 76021760);            //  2,097,152
  float* norm025        = (float*)(ws + 78118912);            //    262,144
  unsigned short* khi   = (unsigned short*)(ws + 78381056);   //  8,388,608
  unsigned short* klo   = (unsigned short*)(ws + 86769664);   //  8,388,608
  unsigned short* vhi   = (unsigned short*)(ws + 95158272);   //  8,388,608
  unsigned short* vlo   = (unsigned short*)(ws + 103546880);  //  8,388,608

  k_prep<<<dim3(T / 64, BHN), 256, 0, stream>>>(qk, v, khi, klo, vhi, vlo, norm025);
  k_bucket<<<dim3(T / 64, BHN, NH), 64, 0, stream>>>(qk, rot, bkts);
  k_sort<<<dim3(NH * BHN), 1024, 0, stream>>>(bkts, perm);
  k_attn6<<<dim3(NB * BHN * NH), 256, 0, stream>>>(khi, klo, vhi, vlo, perm,
                                                   norm025, o_ws, lse_ws);
  k_combine<<<dim3((BHN * T * 16) / 256), 256, 0, stream>>>(o_ws, lse_ws, out);
}

// Round 8
// 138.544 us; speedup vs baseline: 1.9447x; 1.2800x over previous
//
#include <hip/hip_runtime.h>
#include <hip/hip_bf16.h>
#include <hip/hip_fp16.h>
#include <math.h>

#define T 4096
#define NH 8
#define BHN 16
#define NB 64   // buckets per sequence
#define BS 64   // bucket size

using f16x8 = __attribute__((ext_vector_type(8))) _Float16;
using fp16x2_builtin = __attribute__((ext_vector_type(2))) __fp16;
using f32x4 = __attribute__((ext_vector_type(4))) float;

__device__ __forceinline__ f32x4 mfma16f(f16x8 a, f16x8 b, f32x4 c) {
  return __builtin_amdgcn_mfma_f32_16x16x32_f16(a, b, c, 0, 0, 0);
}

// fp32x2 -> fp16x2 RTZ pack (1 inst), elem0 in low half
__device__ __forceinline__ unsigned cvtpk_f16(float a, float b) {
  fp16x2_builtin r = __builtin_amdgcn_cvt_pkrtz(a, b);
  unsigned u; __builtin_memcpy(&u, &r, 4); return u;
}
// fp32x2 -> fp16x2 RNE pack (for prep; memory-bound so VALU free)
__device__ __forceinline__ unsigned pk_h2_rn(float a, float b) {
  __half2 h = __float22half2_rn(make_float2(a, b));
  unsigned u; __builtin_memcpy(&u, &h, 4); return u;
}
__device__ __forceinline__ float f4get(const float4& v, int i) {
  return i == 0 ? v.x : i == 1 ? v.y : i == 2 ? v.z : v.w;
}
__device__ __forceinline__ unsigned u4get(const uint4& v, int i) {
  return i == 0 ? v.x : i == 1 ? v.y : i == 2 ? v.z : v.w;
}

// async global->LDS, 16B per lane, linear LDS dest
__device__ __forceinline__ void async_load16(const void* src, void* dst_lds) {
  __builtin_amdgcn_global_load_lds(
      (const __attribute__((address_space(1))) unsigned int*)src,
      (__attribute__((address_space(3))) unsigned int*)dst_lds, 16, 0, 0);
}

// byte-offset swizzles: rows of 128B / 256B, XOR low row bits into 16B-slot bits
#define SWZ128(row, inb) ((((row)) << 7) + ((inb) ^ ((((row)) & 7) << 4)))
#define SWZ256(row, inb) ((((row)) << 8) + ((inb) ^ ((((row)) & 7) << 4)))

// ---------------------------------------------------------------------------
// K_prep: per (bh, token): k_hat fp16, v fp16, norm025.
// grid (T/64, BH), block 256 (4 threads per token, 16 elems each).
// ---------------------------------------------------------------------------
__global__ __launch_bounds__(256) void k_prep(const float* __restrict__ qk,
                                              const float* __restrict__ v,
                                              unsigned short* __restrict__ khf,
                                              unsigned short* __restrict__ vhf,
                                              float* __restrict__ norm025) {
  const int tid = threadIdx.x;
  const int tok = blockIdx.x * 64 + (tid >> 2);
  const int bh = blockIdx.y;
  const int b = bh >> 3, hh = bh & 7;
  const int q4 = tid & 3;
  const size_t g = ((size_t)b * T + tok) * 512 + hh * 64 + q4 * 16;

  float4 x[4], y[4];
  #pragma unroll
  for (int k = 0; k < 4; ++k) {
    x[k] = *(const float4*)&qk[g + k * 4];
    y[k] = *(const float4*)&v[g + k * 4];
  }
  float ss = 0.f;
  #pragma unroll
  for (int k = 0; k < 4; ++k)
    ss += x[k].x * x[k].x + x[k].y * x[k].y + x[k].z * x[k].z + x[k].w * x[k].w;
  ss += __shfl_xor(ss, 1);
  ss += __shfl_xor(ss, 2);
  const float invn = rsqrtf(ss);

  const size_t ob = ((size_t)bh * T + tok) * 64 + q4 * 16;
  unsigned kw[8], vw[8];
  #pragma unroll
  for (int k = 0; k < 4; ++k) {
    #pragma unroll
    for (int p = 0; p < 2; ++p) {
      float a0 = f4get(x[k], 2 * p) * invn, a1 = f4get(x[k], 2 * p + 1) * invn;
      kw[k * 2 + p] = pk_h2_rn(a0, a1);
      vw[k * 2 + p] = pk_h2_rn(f4get(y[k], 2 * p), f4get(y[k], 2 * p + 1));
    }
  }
  *(uint4*)&khf[ob]     = (uint4){kw[0], kw[1], kw[2], kw[3]};
  *(uint4*)&khf[ob + 8] = (uint4){kw[4], kw[5], kw[6], kw[7]};
  *(uint4*)&vhf[ob]     = (uint4){vw[0], vw[1], vw[2], vw[3]};
  *(uint4*)&vhf[ob + 8] = (uint4){vw[4], vw[5], vw[6], vw[7]};
  if (q4 == 0) norm025[(size_t)bh * T + tok] = 0.125f * ss * invn;
}

// ---------------------------------------------------------------------------
// K1: one-pass LSH buckets: all 8 hashes, 2 per wave. grid (T/64, BH), blk 256.
// rot addresses wave-uniform (readfirstlane) -> scalar loads; qk read ONCE.
// ---------------------------------------------------------------------------
__global__ __launch_bounds__(256) void k_bucket1p(const float* __restrict__ qk,
                                                  const float* __restrict__ rot,
                                                  unsigned char* __restrict__ buckets) {
  __shared__ float sQ[64][65];
  const int tid = threadIdx.x;
  const int t0 = blockIdx.x * 64;
  const int bh = blockIdx.y;
  const int b = bh >> 3, hh = bh & 7;
  const size_t gbase = (size_t)b * ((size_t)T * 512) + (size_t)hh * 64;

  #pragma unroll
  for (int i = 0; i < 4; ++i) {
    int rr = i * 16 + (tid >> 4);
    int cc = (tid & 15) * 4;
    float4 x = *(const float4*)&qk[gbase + (size_t)(t0 + rr) * 512 + cc];
    sQ[rr][cc] = x.x; sQ[rr][cc + 1] = x.y; sQ[rr][cc + 2] = x.z; sQ[rr][cc + 3] = x.w;
  }
  __syncthreads();

  const int wv = __builtin_amdgcn_readfirstlane(tid >> 6);  // wave id (uniform)
  const int tok = tid & 63;
  const int t = t0 + tok;

  float a0[32], a1[32];
  #pragma unroll
  for (int i = 0; i < 32; ++i) { a0[i] = 0.f; a1[i] = 0.f; }
  for (int f = 0; f < 64; ++f) {
    float qv = sQ[tok][f];
    const float* rp = rot + (size_t)f * (NH * 32) + wv * 64;  // hashes 2wv, 2wv+1
    #pragma unroll
    for (int i = 0; i < 32; ++i) {
      a0[i] = fmaf(qv, rp[i], a0[i]);
      a1[i] = fmaf(qv, rp[32 + i], a1[i]);
    }
  }
  #pragma unroll
  for (int h = 0; h < 2; ++h) {
    const float* ac = h ? a1 : a0;
    float maxv = -INFINITY, minv = INFINITY;
    int amax = 0, amin = 0;
    #pragma unroll
    for (int i = 0; i < 32; ++i) {
      if (ac[i] > maxv) { maxv = ac[i]; amax = i; }
      if (ac[i] < minv) { minv = ac[i]; amin = i; }
    }
    int bucket = (maxv >= -minv) ? amax : 32 + amin;
    buckets[((size_t)(2 * wv + h) * BHN + bh) * T + t] = (unsigned char)bucket;
  }
}

// ---------------------------------------------------------------------------
// K2: stable counting argsort per (hash, bh) segment. grid (NH*BH), block 1024.
// ---------------------------------------------------------------------------
__global__ __launch_bounds__(1024) void k_sort(const unsigned char* __restrict__ buckets,
                                               int* __restrict__ perm,
                                               int* __restrict__ perm_inv) {
  __shared__ unsigned short bkt[T];
  __shared__ unsigned short rnk[T];
  __shared__ unsigned int cnt[64 * 64];
  __shared__ unsigned int bbase[64];
  __shared__ unsigned int btot[64];

  const int tid = threadIdx.x;
  const int seg = blockIdx.x;
  const unsigned char* bin = buckets + (size_t)seg * T;

  for (int idx = tid; idx < T; idx += 1024) bkt[idx] = bin[idx];
  __syncthreads();

  const int wave = tid >> 6, lane = tid & 63;
  const unsigned long long lt = (1ull << lane) - 1ull;
  for (int cc = 0; cc < 4; ++cc) {
    int chunk = wave * 4 + cc;
    int e = bkt[chunk * 64 + lane];
    for (int bb = 0; bb < 64; ++bb) {
      unsigned long long m = __ballot(e == bb);
      if (lane == bb) cnt[bb * 64 + chunk] = (unsigned int)__popcll(m);
      if (e == bb) rnk[chunk * 64 + lane] = (unsigned short)__popcll(m & lt);
    }
  }
  __syncthreads();
  if (tid < 64) {
    unsigned int run = 0;
    for (int c = 0; c < 64; ++c) {
      unsigned int v = cnt[tid * 64 + c];
      cnt[tid * 64 + c] = run;
      run += v;
    }
    btot[tid] = run;
  }
  __syncthreads();
  if (tid == 0) {
    unsigned int run = 0;
    for (int bb = 0; bb < 64; ++bb) { bbase[bb] = run; run += btot[bb]; }
  }
  __syncthreads();
  for (int idx = tid; idx < T; idx += 1024) {
    int e = bkt[idx];
    int c = idx >> 6;
    int pos = (int)(bbase[e] + cnt[e * 64 + c] + rnk[idx]);
    perm[(size_t)seg * T + pos] = idx;
    perm_inv[(size_t)seg * T + idx] = pos;
  }
}

// ---------------------------------------------------------------------------
// K3: per-bucket attention, all fp16 single-term. K via global_load_lds;
// V gather + perm-transpose (one pass, 128 tokens); P fp16 RTZ; PV one phase.
// LDS 32KB -> 5 blocks/CU. 3 barriers. grid 8192 (XCD-swizzled), block 256.
// ---------------------------------------------------------------------------
__global__ __launch_bounds__(256, 5) void k_attn7(
    const unsigned short* __restrict__ khf, const unsigned short* __restrict__ vhf,
    const int* __restrict__ perm, const float* __restrict__ norm025,
    __half* __restrict__ o_ws, float* __restrict__ lse_s) {
  __shared__ __align__(16) char smem[32768];
  constexpr int LK  = 0;       // ph1: Khat [128 kv][128B fp16] SWZ128
  constexpr int LP  = 0;       // ph2: P [64 q][256B fp16 = 128 kv] SWZ256
  constexpr int LVT = 16384;   // V^T [64 d][256B fp16 = 128 tokens] SWZ256

  const int tid = threadIdx.x;
  // XCD-aware bijective swizzle (8192 % 8 == 0): XCD x gets hash r = x.
  const int wg = ((int)blockIdx.x & 7) * 1024 + ((int)blockIdx.x >> 3);
  const int n = wg & 63, bh = (wg >> 6) & 15, r = wg >> 10;
  const size_t rowbase = (size_t)bh * T;
  const size_t ps = ((size_t)r * BHN + bh) * T;
  const int base_own = n * 64;
  const int base_prev = ((n + 63) & 63) * 64;

  const int wid = tid >> 6, lane = tid & 63;
  const int lr = lane & 15, lg = lane >> 4;

  const int qtok = perm[ps + base_own + 16 * wid + lr];
  const float scale = norm025[rowbase + qtok];
  int otok[4];
  #pragma unroll
  for (int rr = 0; rr < 4; ++rr)
    otok[rr] = perm[ps + base_own + 16 * wid + 4 * lg + rr];

  // ---- V gather: 2 tokens x 16 d per thread (issue early, in flight) ----
  const int vj0 = (tid & 63) * 2;         // token pair (vj0, vj0+1)
  const int vd0 = (tid >> 6) * 16;        // d range [vd0, vd0+16)
  int vt[2];
  #pragma unroll
  for (int j = 0; j < 2; ++j) {
    int src = (vj0 + j < 64) ? (base_own + vj0 + j) : (base_prev + vj0 + j - 64);
    vt[j] = perm[ps + src];
  }
  uint4 VA0, VA1, VB0, VB1;
  {
    const uint4* pa = (const uint4*)&vhf[(rowbase + (size_t)vt[0]) * 64 + vd0];
    const uint4* pb = (const uint4*)&vhf[(rowbase + (size_t)vt[1]) * 64 + vd0];
    VA0 = pa[0]; VA1 = pa[1];
    VB0 = pb[0]; VB1 = pb[1];
  }

  // ---- K staging: global_load_lds, linear dest + inverse-swizzled source ----
  #pragma unroll
  for (int it = 0; it < 4; ++it) {
    int unit = it * 256 + tid;
    int row = unit >> 3, sl = unit & 7;
    int ssl = sl ^ (row & 7);
    int src = (row < 64) ? (base_own + row) : (base_prev + (row - 64));
    int tokr = perm[ps + src];
    async_load16(&khf[(rowbase + (size_t)tokr) * 64 + ssl * 8], smem + LK + unit * 16);
  }
  __syncthreads();  // s2: K staged

  // B frag = own q row, held in regs before P overlays LK
  f16x8 bq[2];
  #pragma unroll
  for (int ks = 0; ks < 2; ++ks)
    bq[ks] = *(const f16x8*)(smem + LK + SWZ128(16 * wid + lr, lg * 16 + ks * 64));

  // ---- QK: S^T[kv][q] = K . Q^T, 16 MFMA ----
  f32x4 c[8];
  #pragma unroll
  for (int t = 0; t < 8; ++t) c[t] = (f32x4){0.f, 0.f, 0.f, 0.f};
  #pragma unroll
  for (int t = 0; t < 8; ++t) {
    #pragma unroll
    for (int ks = 0; ks < 2; ++ks) {
      f16x8 ak = *(const f16x8*)(smem + LK + SWZ128(16 * t + lr, lg * 16 + ks * 64));
      c[t] = mfma16f(ak, bq[ks], c[t]);
    }
  }

  // ---- V^T -> LVT (fresh region, hidden under QK; read only after s4) ----
  #pragma unroll
  for (int dd = 0; dd < 16; ++dd) {
    unsigned aw = (dd < 8) ? u4get(VA0, dd >> 1) : u4get(VA1, (dd - 8) >> 1);
    unsigned bw = (dd < 8) ? u4get(VB0, dd >> 1) : u4get(VB1, (dd - 8) >> 1);
    unsigned w = (dd & 1) ? __builtin_amdgcn_perm(bw, aw, 0x07060302u)
                          : __builtin_amdgcn_perm(bw, aw, 0x05040100u);
    *(unsigned*)(smem + LVT + SWZ256(vd0 + dd, vj0 * 2)) = w;
  }

  // ---- self-mask: position diagonal (q row == kv row in 0..63) ----
  #pragma unroll
  for (int t = 0; t < 4; ++t) {
    #pragma unroll
    for (int rr = 0; rr < 4; ++rr)
      if (16 * t + 4 * lg + rr == 16 * wid + lr) c[t][rr] = -1e30f;
  }

  // ---- softmax (q fixed per lane; reduce lanes xor16/32) ----
  float mm = -1e30f;
  #pragma unroll
  for (int t = 0; t < 8; ++t)
    mm = fmaxf(mm, fmaxf(fmaxf(c[t][0], c[t][1]), fmaxf(c[t][2], c[t][3])));
  mm = fmaxf(mm, __shfl_xor(mm, 16));
  mm = fmaxf(mm, __shfl_xor(mm, 32));
  const float sl2e = scale * 1.4426950408889634f;
  float ll = 0.f;
  #pragma unroll
  for (int t = 0; t < 8; ++t) {
    #pragma unroll
    for (int rr = 0; rr < 4; ++rr) {
      float e = exp2f((c[t][rr] - mm) * sl2e);
      c[t][rr] = e;
      ll += e;
    }
  }
  ll += __shfl_xor(ll, 16);
  ll += __shfl_xor(ll, 32);
  // lse in SORTED order: contiguous 256B per block (no scatter)
  if (lg == 0) lse_s[ps + base_own + 16 * wid + lr] = scale * mm + __logf(ll);

  __syncthreads();  // s3: all LK reads done

  // ---- P (unnormalized fp16, RTZ pack) over LK as [64 q][256B] ----
  {
    const int prow = 16 * wid + lr;
    #pragma unroll
    for (int t = 0; t < 8; ++t) {
      unsigned u01 = cvtpk_f16(c[t][0], c[t][1]);
      unsigned u23 = cvtpk_f16(c[t][2], c[t][3]);
      *(uint2*)(smem + LP + SWZ256(prow, 32 * t + 8 * lg)) = make_uint2(u01, u23);
    }
  }
  __syncthreads();  // s4: P + V^T staged

  // ---- PV: A = P row (q = 16w+lr), B = V^T rows (d), 16 MFMA ----
  f16x8 pa[4];
  #pragma unroll
  for (int ks = 0; ks < 4; ++ks)
    pa[ks] = *(const f16x8*)(smem + LP + SWZ256(16 * wid + lr, ks * 64 + lg * 16));
  f32x4 o[4];
  #pragma unroll
  for (int td = 0; td < 4; ++td) o[td] = (f32x4){0.f, 0.f, 0.f, 0.f};
  #pragma unroll
  for (int td = 0; td < 4; ++td) {
    #pragma unroll
    for (int ks = 0; ks < 4; ++ks) {
      f16x8 bv = *(const f16x8*)(smem + LVT + SWZ256(16 * td + lr, lg * 16 + ks * 64));
      o[td] = mfma16f(pa[ks], bv, o[td]);
    }
  }

  // ---- normalize + direct fp16 O stores ----
  float rl[4];
  #pragma unroll
  for (int rr = 0; rr < 4; ++rr) rl[rr] = 1.0f / __shfl(ll, 4 * lg + rr);
  #pragma unroll
  for (int rr = 0; rr < 4; ++rr) {
    size_t gb = (ps + (size_t)otok[rr]) * 64 + lr;
    #pragma unroll
    for (int td = 0; td < 4; ++td)
      o_ws[gb + 16 * td] = __float2half(o[td][rr] * rl[rr]);
  }
}

// ---------------------------------------------------------------------------
// K4: combine hashes. lse gathered via perm_inv (lse stored in sorted order).
// grid (BH*T*16/256), block 256.
// ---------------------------------------------------------------------------
__global__ __launch_bounds__(256) void k_combine(const __half* __restrict__ o_ws,
                                                 const float* __restrict__ lse_s,
                                                 const int* __restrict__ perm_inv,
                                                 float* __restrict__ out) {
  const int gid = blockIdx.x * 256 + threadIdx.x;
  const int d4 = (gid & 15) * 4;
  const int row = gid >> 4;   // bh*T + t
  const int bh = row >> 12;
  const int t = row & (T - 1);

  float ls[8];
  float mm = -INFINITY;
  #pragma unroll
  for (int r = 0; r < 8; ++r) {
    size_t sb = ((size_t)r * BHN + bh) * T;
    int pos = perm_inv[sb + t];
    ls[r] = lse_s[sb + pos];
    mm = fmaxf(mm, ls[r]);
  }
  float sum = 0.f;
  #pragma unroll
  for (int r = 0; r < 8; ++r) { ls[r] = __expf(ls[r] - mm); sum += ls[r]; }
  float rcp = 1.0f / sum;

  float a0 = 0.f, a1 = 0.f, a2 = 0.f, a3 = 0.f;
  #pragma unroll
  for (int r = 0; r < 8; ++r) {
    const __half* op = &o_ws[(((size_t)r * BHN + bh) * T + t) * 64 + d4];
    __half2 h01 = *(const __half2*)&op[0];
    __half2 h23 = *(const __half2*)&op[2];
    float2 f01 = __half22float2(h01);
    float2 f23 = __half22float2(h23);
    a0 += ls[r] * f01.x; a1 += ls[r] * f01.y;
    a2 += ls[r] * f23.x; a3 += ls[r] * f23.y;
  }
  const int b = bh >> 3, hh = bh & 7;
  *(float4*)&out[(((size_t)b * T + t) * 8 + hh) * 64 + d4] =
      make_float4(a0 * rcp, a1 * rcp, a2 * rcp, a3 * rcp);
}

// ---------------------------------------------------------------------------
extern "C" void kernel_launch(void* const* d_in, const int* in_sizes, int n_in,
                              void* d_out, int out_size, void* d_ws, size_t ws_size,
                              hipStream_t stream) {
  const float* qk  = (const float*)d_in[0];
  const float* v   = (const float*)d_in[1];
  const float* rot = (const float*)d_in[2];
  float* out = (float*)d_out;

  // workspace layout (bytes) — total 103,546,880 (within proven budget)
  char* ws = (char*)d_ws;
  __half* o_ws          = (__half*)(ws);                      // 67,108,864
  int* perm             = (int*)(ws + 67108864);              //  8,388,608
  int* perm_inv         = (int*)(ws + 75497472);              //  8,388,608
  unsigned char* bkts   = (unsigned char*)(ws + 83886080);    //    524,288
  float* lse_s          = (float*)(ws + 84410368);            //  2,097,152
  float* norm025        = (float*)(ws + 86507520);            //    262,144
  unsigned short* khf   = (unsigned short*)(ws + 86769664);   //  8,388,608
  unsigned short* vhf   = (unsigned short*)(ws + 95158272);   //  8,388,608

  k_prep<<<dim3(T / 64, BHN), 256, 0, stream>>>(qk, v, khf, vhf, norm025);
  k_bucket1p<<<dim3(T / 64, BHN), 256, 0, stream>>>(qk, rot, bkts);
  k_sort<<<dim3(NH * BHN), 1024, 0, stream>>>(bkts, perm, perm_inv);
  k_attn7<<<dim3(NB * BHN * NH), 256, 0, stream>>>(khf, vhf, perm, norm025,
                                                   o_ws, lse_s);
  k_combine<<<dim3((BHN * T * 16) / 256), 256, 0, stream>>>(o_ws, lse_s, perm_inv, out);
}

// Round 9
// 129.206 us; speedup vs baseline: 2.0852x; 1.0723x over previous
//
#include <hip/hip_runtime.h>
#include <hip/hip_bf16.h>
#include <hip/hip_fp16.h>
#include <math.h>

#define T 4096
#define NH 8
#define BHN 16
#define NB 64   // buckets per sequence
#define BS 64   // bucket size

using f16x8 = __attribute__((ext_vector_type(8))) _Float16;
using fp16x2_builtin = __attribute__((ext_vector_type(2))) __fp16;
using f32x4 = __attribute__((ext_vector_type(4))) float;

__device__ __forceinline__ f32x4 mfma16f(f16x8 a, f16x8 b, f32x4 c) {
  return __builtin_amdgcn_mfma_f32_16x16x32_f16(a, b, c, 0, 0, 0);
}

// fp32x2 -> fp16x2 RTZ pack (1 inst), elem0 in low half
__device__ __forceinline__ unsigned cvtpk_f16(float a, float b) {
  fp16x2_builtin r = __builtin_amdgcn_cvt_pkrtz(a, b);
  unsigned u; __builtin_memcpy(&u, &r, 4); return u;
}
// fp32x2 -> fp16x2 RNE pack (for prep; memory-bound so VALU free)
__device__ __forceinline__ unsigned pk_h2_rn(float a, float b) {
  __half2 h = __float22half2_rn(make_float2(a, b));
  unsigned u; __builtin_memcpy(&u, &h, 4); return u;
}
__device__ __forceinline__ float f4get(const float4& v, int i) {
  return i == 0 ? v.x : i == 1 ? v.y : i == 2 ? v.z : v.w;
}
__device__ __forceinline__ unsigned u4get(const uint4& v, int i) {
  return i == 0 ? v.x : i == 1 ? v.y : i == 2 ? v.z : v.w;
}

// async global->LDS, 16B per lane, linear LDS dest
__device__ __forceinline__ void async_load16(const void* src, void* dst_lds) {
  __builtin_amdgcn_global_load_lds(
      (const __attribute__((address_space(1))) unsigned int*)src,
      (__attribute__((address_space(3))) unsigned int*)dst_lds, 16, 0, 0);
}

// byte-offset swizzles: rows of 128B / 256B, XOR low row bits into 16B-slot bits
#define SWZ128(row, inb) ((((row)) << 7) + ((inb) ^ ((((row)) & 7) << 4)))
#define SWZ256(row, inb) ((((row)) << 8) + ((inb) ^ ((((row)) & 7) << 4)))

// ---------------------------------------------------------------------------
// K1: fused prep + bucket. One qk read: tile in LDS feeds (a) fp16 k_hat/v
// conversion + norm025, (b) all-8-hash LSH bucketing (2 hashes per wave).
// grid (T/64, BH), block 256.
// ---------------------------------------------------------------------------
__global__ __launch_bounds__(256) void k_prepbkt(const float* __restrict__ qk,
                                                 const float* __restrict__ v,
                                                 const float* __restrict__ rot,
                                                 unsigned short* __restrict__ khf,
                                                 unsigned short* __restrict__ vhf,
                                                 float* __restrict__ norm025,
                                                 unsigned char* __restrict__ buckets) {
  __shared__ float sQ[64][65];   // 65-pitch: bucket loop (hot) is 2-way-free
  const int tid = threadIdx.x;
  const int t0 = blockIdx.x * 64;
  const int bh = blockIdx.y;
  const int b = bh >> 3, hh = bh & 7;
  const size_t gbase = (size_t)b * ((size_t)T * 512) + (size_t)hh * 64;

  // ---- stage qk tile (single HBM read of qk) ----
  #pragma unroll
  for (int i = 0; i < 4; ++i) {
    int rr = i * 16 + (tid >> 4);
    int cc = (tid & 15) * 4;
    float4 x = *(const float4*)&qk[gbase + (size_t)(t0 + rr) * 512 + cc];
    sQ[rr][cc] = x.x; sQ[rr][cc + 1] = x.y; sQ[rr][cc + 2] = x.z; sQ[rr][cc + 3] = x.w;
  }
  __syncthreads();

  // ---- prep: 4 threads per token, 16 elems each ----
  {
    const int tok = tid >> 2, q4 = tid & 3;
    float x[16];
    #pragma unroll
    for (int k = 0; k < 16; ++k) x[k] = sQ[tok][q4 * 16 + k];
    float4 y[4];
    const size_t gv = gbase + (size_t)(t0 + tok) * 512 + q4 * 16;
    #pragma unroll
    for (int k = 0; k < 4; ++k) y[k] = *(const float4*)&v[gv + k * 4];

    float ss = 0.f;
    #pragma unroll
    for (int k = 0; k < 16; ++k) ss += x[k] * x[k];
    ss += __shfl_xor(ss, 1);
    ss += __shfl_xor(ss, 2);
    const float invn = rsqrtf(ss);

    const size_t ob = ((size_t)bh * T + (t0 + tok)) * 64 + q4 * 16;
    unsigned kw[8], vw[8];
    #pragma unroll
    for (int p = 0; p < 8; ++p) {
      kw[p] = pk_h2_rn(x[2 * p] * invn, x[2 * p + 1] * invn);
      vw[p] = pk_h2_rn(f4get(y[p >> 1], (p & 1) * 2), f4get(y[p >> 1], (p & 1) * 2 + 1));
    }
    *(uint4*)&khf[ob]     = (uint4){kw[0], kw[1], kw[2], kw[3]};
    *(uint4*)&khf[ob + 8] = (uint4){kw[4], kw[5], kw[6], kw[7]};
    *(uint4*)&vhf[ob]     = (uint4){vw[0], vw[1], vw[2], vw[3]};
    *(uint4*)&vhf[ob + 8] = (uint4){vw[4], vw[5], vw[6], vw[7]};
    if (q4 == 0) norm025[(size_t)bh * T + (t0 + tok)] = 0.125f * ss * invn;
  }

  // ---- bucket: wave wv handles hashes 2wv, 2wv+1; lane = token ----
  const int wv = __builtin_amdgcn_readfirstlane(tid >> 6);
  const int tok = tid & 63;
  const int t = t0 + tok;

  float a0[32], a1[32];
  #pragma unroll
  for (int i = 0; i < 32; ++i) { a0[i] = 0.f; a1[i] = 0.f; }
  for (int f = 0; f < 64; ++f) {
    float qv = sQ[tok][f];
    const float* rp = rot + (size_t)f * (NH * 32) + wv * 64;  // hashes 2wv, 2wv+1
    #pragma unroll
    for (int i = 0; i < 32; ++i) {
      a0[i] = fmaf(qv, rp[i], a0[i]);
      a1[i] = fmaf(qv, rp[32 + i], a1[i]);
    }
  }
  #pragma unroll
  for (int h = 0; h < 2; ++h) {
    const float* ac = h ? a1 : a0;
    float maxv = -INFINITY, minv = INFINITY;
    int amax = 0, amin = 0;
    #pragma unroll
    for (int i = 0; i < 32; ++i) {
      if (ac[i] > maxv) { maxv = ac[i]; amax = i; }
      if (ac[i] < minv) { minv = ac[i]; amin = i; }
    }
    int bucket = (maxv >= -minv) ? amax : 32 + amin;
    buckets[((size_t)(2 * wv + h) * BHN + bh) * T + t] = (unsigned char)bucket;
  }
}

// ---------------------------------------------------------------------------
// K2: stable counting argsort per (hash, bh) segment. grid (NH*BH), block 1024.
// ---------------------------------------------------------------------------
__global__ __launch_bounds__(1024) void k_sort(const unsigned char* __restrict__ buckets,
                                               int* __restrict__ perm) {
  __shared__ unsigned short bkt[T];
  __shared__ unsigned short rnk[T];
  __shared__ unsigned int cnt[64 * 64];
  __shared__ unsigned int bbase[64];
  __shared__ unsigned int btot[64];

  const int tid = threadIdx.x;
  const int seg = blockIdx.x;
  const unsigned char* bin = buckets + (size_t)seg * T;

  for (int idx = tid; idx < T; idx += 1024) bkt[idx] = bin[idx];
  __syncthreads();

  const int wave = tid >> 6, lane = tid & 63;
  const unsigned long long lt = (1ull << lane) - 1ull;
  for (int cc = 0; cc < 4; ++cc) {
    int chunk = wave * 4 + cc;
    int e = bkt[chunk * 64 + lane];
    for (int bb = 0; bb < 64; ++bb) {
      unsigned long long m = __ballot(e == bb);
      if (lane == bb) cnt[bb * 64 + chunk] = (unsigned int)__popcll(m);
      if (e == bb) rnk[chunk * 64 + lane] = (unsigned short)__popcll(m & lt);
    }
  }
  __syncthreads();
  if (tid < 64) {
    unsigned int run = 0;
    for (int c = 0; c < 64; ++c) {
      unsigned int v = cnt[tid * 64 + c];
      cnt[tid * 64 + c] = run;
      run += v;
    }
    btot[tid] = run;
  }
  __syncthreads();
  if (tid == 0) {
    unsigned int run = 0;
    for (int bb = 0; bb < 64; ++bb) { bbase[bb] = run; run += btot[bb]; }
  }
  __syncthreads();
  for (int idx = tid; idx < T; idx += 1024) {
    int e = bkt[idx];
    int c = idx >> 6;
    int pos = (int)(bbase[e] + cnt[e * 64 + c] + rnk[idx]);
    perm[(size_t)seg * T + pos] = idx;
  }
}

// ---------------------------------------------------------------------------
// K3: per-bucket attention, fp16 single-term, MAX-FREE softmax (scores
// bounded by scale <= ~2). K via global_load_lds; V gather + perm transpose;
// P fp16 RTZ. LDS 32KB -> 5 blocks/CU. grid 8192 (XCD-swizzled), block 256.
// ---------------------------------------------------------------------------
__global__ __launch_bounds__(256, 5) void k_attn9(
    const unsigned short* __restrict__ khf, const unsigned short* __restrict__ vhf,
    const int* __restrict__ perm, const float* __restrict__ norm025,
    __half* __restrict__ o_ws, float* __restrict__ lse_ws) {
  __shared__ __align__(16) char smem[32768];
  constexpr int LK  = 0;       // ph1: Khat [128 kv][128B fp16] SWZ128
  constexpr int LP  = 0;       // ph2: P [64 q][256B fp16 = 128 kv] SWZ256
  constexpr int LVT = 16384;   // V^T [64 d][256B fp16 = 128 tokens] SWZ256

  const int tid = threadIdx.x;
  // XCD-aware bijective swizzle (8192 % 8 == 0): XCD x gets hash r = x.
  const int wg = ((int)blockIdx.x & 7) * 1024 + ((int)blockIdx.x >> 3);
  const int n = wg & 63, bh = (wg >> 6) & 15, r = wg >> 10;
  const size_t rowbase = (size_t)bh * T;
  const size_t ps = ((size_t)r * BHN + bh) * T;
  const int base_own = n * 64;
  const int base_prev = ((n + 63) & 63) * 64;

  const int wid = tid >> 6, lane = tid & 63;
  const int lr = lane & 15, lg = lane >> 4;

  const int qtok = perm[ps + base_own + 16 * wid + lr];
  const float scale = norm025[rowbase + qtok];

  // ---- V gather: 2 tokens x 16 d per thread (issue early, in flight) ----
  const int vj0 = (tid & 63) * 2;         // token pair (vj0, vj0+1)
  const int vd0 = (tid >> 6) * 16;        // d range [vd0, vd0+16)
  int vt[2];
  #pragma unroll
  for (int j = 0; j < 2; ++j) {
    int src = (vj0 + j < 64) ? (base_own + vj0 + j) : (base_prev + vj0 + j - 64);
    vt[j] = perm[ps + src];
  }
  uint4 VA0, VA1, VB0, VB1;
  {
    const uint4* pa = (const uint4*)&vhf[(rowbase + (size_t)vt[0]) * 64 + vd0];
    const uint4* pb = (const uint4*)&vhf[(rowbase + (size_t)vt[1]) * 64 + vd0];
    VA0 = pa[0]; VA1 = pa[1];
    VB0 = pb[0]; VB1 = pb[1];
  }

  // ---- K staging: global_load_lds, linear dest + inverse-swizzled source ----
  #pragma unroll
  for (int it = 0; it < 4; ++it) {
    int unit = it * 256 + tid;
    int row = unit >> 3, sl = unit & 7;
    int ssl = sl ^ (row & 7);
    int src = (row < 64) ? (base_own + row) : (base_prev + (row - 64));
    int tokr = perm[ps + src];
    async_load16(&khf[(rowbase + (size_t)tokr) * 64 + ssl * 8], smem + LK + unit * 16);
  }
  __syncthreads();  // s2: K staged

  // B frag = own q row, held in regs before P overlays LK
  f16x8 bq[2];
  #pragma unroll
  for (int ks = 0; ks < 2; ++ks)
    bq[ks] = *(const f16x8*)(smem + LK + SWZ128(16 * wid + lr, lg * 16 + ks * 64));

  // ---- QK: S^T[kv][q] = K . Q^T, 16 MFMA ----
  f32x4 c[8];
  #pragma unroll
  for (int t = 0; t < 8; ++t) c[t] = (f32x4){0.f, 0.f, 0.f, 0.f};
  #pragma unroll
  for (int t = 0; t < 8; ++t) {
    #pragma unroll
    for (int ks = 0; ks < 2; ++ks) {
      f16x8 ak = *(const f16x8*)(smem + LK + SWZ128(16 * t + lr, lg * 16 + ks * 64));
      c[t] = mfma16f(ak, bq[ks], c[t]);
    }
  }

  // ---- V^T -> LVT (fresh region, hidden under QK; read only after s4) ----
  #pragma unroll
  for (int dd = 0; dd < 16; ++dd) {
    unsigned aw = (dd < 8) ? u4get(VA0, dd >> 1) : u4get(VA1, (dd - 8) >> 1);
    unsigned bw = (dd < 8) ? u4get(VB0, dd >> 1) : u4get(VB1, (dd - 8) >> 1);
    unsigned w = (dd & 1) ? __builtin_amdgcn_perm(bw, aw, 0x07060302u)
                          : __builtin_amdgcn_perm(bw, aw, 0x05040100u);
    *(unsigned*)(smem + LVT + SWZ256(vd0 + dd, vj0 * 2)) = w;
  }

  // ---- self-mask: position diagonal (q row == kv row in 0..63) ----
  #pragma unroll
  for (int t = 0; t < 4; ++t) {
    #pragma unroll
    for (int rr = 0; rr < 4; ++rr)
      if (16 * t + 4 * lg + rr == 16 * wid + lr) c[t][rr] = -1e30f;
  }

  // ---- MAX-FREE softmax: |score| <= scale (<= ~2), no overflow possible ----
  const float sl2e = scale * 1.4426950408889634f;
  float ll = 0.f;
  #pragma unroll
  for (int t = 0; t < 8; ++t) {
    #pragma unroll
    for (int rr = 0; rr < 4; ++rr) {
      float e = exp2f(c[t][rr] * sl2e);
      c[t][rr] = e;
      ll += e;
    }
  }
  ll += __shfl_xor(ll, 16);
  ll += __shfl_xor(ll, 32);
  if (lg == 0) lse_ws[ps + qtok] = __logf(ll);

  __syncthreads();  // s3: all LK reads done

  // ---- P (unnormalized fp16, RTZ pack) over LK as [64 q][256B] ----
  {
    const int prow = 16 * wid + lr;
    #pragma unroll
    for (int t = 0; t < 8; ++t) {
      unsigned u01 = cvtpk_f16(c[t][0], c[t][1]);
      unsigned u23 = cvtpk_f16(c[t][2], c[t][3]);
      *(uint2*)(smem + LP + SWZ256(prow, 32 * t + 8 * lg)) = make_uint2(u01, u23);
    }
  }
  __syncthreads();  // s4: P + V^T staged

  // ---- PV: A = P row (q = 16w+lr), B = V^T rows (d), 16 MFMA ----
  f16x8 pa[4];
  #pragma unroll
  for (int ks = 0; ks < 4; ++ks)
    pa[ks] = *(const f16x8*)(smem + LP + SWZ256(16 * wid + lr, ks * 64 + lg * 16));
  f32x4 o[4];
  #pragma unroll
  for (int td = 0; td < 4; ++td) o[td] = (f32x4){0.f, 0.f, 0.f, 0.f};
  #pragma unroll
  for (int td = 0; td < 4; ++td) {
    #pragma unroll
    for (int ks = 0; ks < 4; ++ks) {
      f16x8 bv = *(const f16x8*)(smem + LVT + SWZ256(16 * td + lr, lg * 16 + ks * 64));
      o[td] = mfma16f(pa[ks], bv, o[td]);
    }
  }

  // ---- normalize + direct fp16 O stores (otok via shuffle from qtok) ----
  #pragma unroll
  for (int rr = 0; rr < 4; ++rr) {
    float rl = 1.0f / __shfl(ll, 4 * lg + rr);
    int otok = __shfl(qtok, 4 * lg + rr);
    size_t gb = (ps + (size_t)otok) * 64 + lr;
    #pragma unroll
    for (int td = 0; td < 4; ++td)
      o_ws[gb + 16 * td] = __float2half(o[td][rr] * rl);
  }
}

// ---------------------------------------------------------------------------
// K4: combine hashes (fp16 o_ws, direct lse loads). grid (BH*T*16/256), blk 256.
// ---------------------------------------------------------------------------
__global__ __launch_bounds__(256) void k_combine(const __half* __restrict__ o_ws,
                                                 const float* __restrict__ lse_ws,
                                                 float* __restrict__ out) {
  const int gid = blockIdx.x * 256 + threadIdx.x;
  const int d4 = (gid & 15) * 4;
  const int row = gid >> 4;   // bh*T + t
  const int bh = row >> 12;
  const int t = row & (T - 1);

  float ls[8];
  float mm = -INFINITY;
  #pragma unroll
  for (int r = 0; r < 8; ++r) {
    ls[r] = lse_ws[((size_t)r * BHN + bh) * T + t];
    mm = fmaxf(mm, ls[r]);
  }
  float sum = 0.f;
  #pragma unroll
  for (int r = 0; r < 8; ++r) { ls[r] = __expf(ls[r] - mm); sum += ls[r]; }
  float rcp = 1.0f / sum;

  float a0 = 0.f, a1 = 0.f, a2 = 0.f, a3 = 0.f;
  #pragma unroll
  for (int r = 0; r < 8; ++r) {
    const __half* op = &o_ws[(((size_t)r * BHN + bh) * T + t) * 64 + d4];
    __half2 h01 = *(const __half2*)&op[0];
    __half2 h23 = *(const __half2*)&op[2];
    float2 f01 = __half22float2(h01);
    float2 f23 = __half22float2(h23);
    a0 += ls[r] * f01.x; a1 += ls[r] * f01.y;
    a2 += ls[r] * f23.x; a3 += ls[r] * f23.y;
  }
  const int b = bh >> 3, hh = bh & 7;
  *(float4*)&out[(((size_t)b * T + t) * 8 + hh) * 64 + d4] =
      make_float4(a0 * rcp, a1 * rcp, a2 * rcp, a3 * rcp);
}

// ---------------------------------------------------------------------------
extern "C" void kernel_launch(void* const* d_in, const int* in_sizes, int n_in,
                              void* d_out, int out_size, void* d_ws, size_t ws_size,
                              hipStream_t stream) {
  const float* qk  = (const float*)d_in[0];
  const float* v   = (const float*)d_in[1];
  const float* rot = (const float*)d_in[2];
  float* out = (float*)d_out;

  // workspace layout (bytes) — total 95,158,272 + 8,388,608 (within budget)
  char* ws = (char*)d_ws;
  __half* o_ws          = (__half*)(ws);                      // 67,108,864
  int* perm             = (int*)(ws + 67108864);              //  8,388,608
  unsigned char* bkts   = (unsigned char*)(ws + 75497472);    //    524,288
  float* lse_ws         = (float*)(ws + 76021760);            //  2,097,152
  float* norm025        = (float*)(ws + 78118912);            //    262,144
  unsigned short* khf   = (unsigned short*)(ws + 78381056);   //  8,388,608
  unsigned short* vhf   = (unsigned short*)(ws + 86769664);   //  8,388,608

  k_prepbkt<<<dim3(T / 64, BHN), 256, 0, stream>>>(qk, v, rot, khf, vhf, norm025, bkts);
  k_sort<<<dim3(NH * BHN), 1024, 0, stream>>>(bkts, perm);
  k_attn9<<<dim3(NB * BHN * NH), 256, 0, stream>>>(khf, vhf, perm, norm025,
                                                   o_ws, lse_ws);
  k_combine<<<dim3((BHN * T * 16) / 256), 256, 0, stream>>>(o_ws, lse_ws, out);
}

// Round 11
// 128.425 us; speedup vs baseline: 2.0979x; 1.0061x over previous
//
#include <hip/hip_runtime.h>
#include <hip/hip_bf16.h>
#include <hip/hip_fp16.h>
#include <math.h>

#define T 4096
#define NH 8
#define BHN 16
#define NB 64   // buckets per sequence
#define BS 64   // bucket size

using f16x8 = __attribute__((ext_vector_type(8))) _Float16;
using fp16x2_builtin = __attribute__((ext_vector_type(2))) __fp16;
using f32x4 = __attribute__((ext_vector_type(4))) float;

__device__ __forceinline__ f32x4 mfma16f(f16x8 a, f16x8 b, f32x4 c) {
  return __builtin_amdgcn_mfma_f32_16x16x32_f16(a, b, c, 0, 0, 0);
}

// fp32x2 -> fp16x2 RTZ pack (1 inst), elem0 in low half
__device__ __forceinline__ unsigned cvtpk_f16(float a, float b) {
  fp16x2_builtin r = __builtin_amdgcn_cvt_pkrtz(a, b);
  unsigned u; __builtin_memcpy(&u, &r, 4); return u;
}
// fp32x2 -> fp16x2 RNE pack (for prep; memory-bound so VALU free)
__device__ __forceinline__ unsigned pk_h2_rn(float a, float b) {
  __half2 h = __float22half2_rn(make_float2(a, b));
  unsigned u; __builtin_memcpy(&u, &h, 4); return u;
}
__device__ __forceinline__ float f4get(const float4& v, int i) {
  return i == 0 ? v.x : i == 1 ? v.y : i == 2 ? v.z : v.w;
}
__device__ __forceinline__ unsigned u4get(const uint4& v, int i) {
  return i == 0 ? v.x : i == 1 ? v.y : i == 2 ? v.z : v.w;
}

// async global->LDS, 16B per lane, linear LDS dest
__device__ __forceinline__ void async_load16(const void* src, void* dst_lds) {
  __builtin_amdgcn_global_load_lds(
      (const __attribute__((address_space(1))) unsigned int*)src,
      (__attribute__((address_space(3))) unsigned int*)dst_lds, 16, 0, 0);
}

// byte-offset swizzles: rows of 128B / 256B, XOR low row bits into 16B-slot bits
#define SWZ128(row, inb) ((((row)) << 7) + ((inb) ^ ((((row)) & 7) << 4)))
#define SWZ256(row, inb) ((((row)) << 8) + ((inb) ^ ((((row)) & 7) << 4)))

// ---------------------------------------------------------------------------
// K1: fused prep + bucket (one qk read). grid (T/64, BH), block 256.
// ---------------------------------------------------------------------------
__global__ __launch_bounds__(256) void k_prepbkt(const float* __restrict__ qk,
                                                 const float* __restrict__ v,
                                                 const float* __restrict__ rot,
                                                 unsigned short* __restrict__ khf,
                                                 unsigned short* __restrict__ vhf,
                                                 float* __restrict__ norm025,
                                                 unsigned char* __restrict__ buckets) {
  __shared__ float sQ[64][65];   // 65-pitch: bucket loop (hot) is 2-way-free
  const int tid = threadIdx.x;
  const int t0 = blockIdx.x * 64;
  const int bh = blockIdx.y;
  const int b = bh >> 3, hh = bh & 7;
  const size_t gbase = (size_t)b * ((size_t)T * 512) + (size_t)hh * 64;

  #pragma unroll
  for (int i = 0; i < 4; ++i) {
    int rr = i * 16 + (tid >> 4);
    int cc = (tid & 15) * 4;
    float4 x = *(const float4*)&qk[gbase + (size_t)(t0 + rr) * 512 + cc];
    sQ[rr][cc] = x.x; sQ[rr][cc + 1] = x.y; sQ[rr][cc + 2] = x.z; sQ[rr][cc + 3] = x.w;
  }
  __syncthreads();

  // ---- prep: 4 threads per token, 16 elems each ----
  {
    const int tok = tid >> 2, q4 = tid & 3;
    float x[16];
    #pragma unroll
    for (int k = 0; k < 16; ++k) x[k] = sQ[tok][q4 * 16 + k];
    float4 y[4];
    const size_t gv = gbase + (size_t)(t0 + tok) * 512 + q4 * 16;
    #pragma unroll
    for (int k = 0; k < 4; ++k) y[k] = *(const float4*)&v[gv + k * 4];

    float ss = 0.f;
    #pragma unroll
    for (int k = 0; k < 16; ++k) ss += x[k] * x[k];
    ss += __shfl_xor(ss, 1);
    ss += __shfl_xor(ss, 2);
    const float invn = rsqrtf(ss);

    const size_t ob = ((size_t)bh * T + (t0 + tok)) * 64 + q4 * 16;
    unsigned kw[8], vw[8];
    #pragma unroll
    for (int p = 0; p < 8; ++p) {
      kw[p] = pk_h2_rn(x[2 * p] * invn, x[2 * p + 1] * invn);
      vw[p] = pk_h2_rn(f4get(y[p >> 1], (p & 1) * 2), f4get(y[p >> 1], (p & 1) * 2 + 1));
    }
    *(uint4*)&khf[ob]     = (uint4){kw[0], kw[1], kw[2], kw[3]};
    *(uint4*)&khf[ob + 8] = (uint4){kw[4], kw[5], kw[6], kw[7]};
    *(uint4*)&vhf[ob]     = (uint4){vw[0], vw[1], vw[2], vw[3]};
    *(uint4*)&vhf[ob + 8] = (uint4){vw[4], vw[5], vw[6], vw[7]};
    if (q4 == 0) norm025[(size_t)bh * T + (t0 + tok)] = 0.125f * ss * invn;
  }

  // ---- bucket: wave wv handles hashes 2wv, 2wv+1; lane = token ----
  const int wv = __builtin_amdgcn_readfirstlane(tid >> 6);
  const int tok = tid & 63;
  const int t = t0 + tok;

  float a0[32], a1[32];
  #pragma unroll
  for (int i = 0; i < 32; ++i) { a0[i] = 0.f; a1[i] = 0.f; }
  for (int f = 0; f < 64; ++f) {
    float qv = sQ[tok][f];
    const float* rp = rot + (size_t)f * (NH * 32) + wv * 64;
    #pragma unroll
    for (int i = 0; i < 32; ++i) {
      a0[i] = fmaf(qv, rp[i], a0[i]);
      a1[i] = fmaf(qv, rp[32 + i], a1[i]);
    }
  }
  #pragma unroll
  for (int h = 0; h < 2; ++h) {
    const float* ac = h ? a1 : a0;
    float maxv = -INFINITY, minv = INFINITY;
    int amax = 0, amin = 0;
    #pragma unroll
    for (int i = 0; i < 32; ++i) {
      if (ac[i] > maxv) { maxv = ac[i]; amax = i; }
      if (ac[i] < minv) { minv = ac[i]; amin = i; }
    }
    int bucket = (maxv >= -minv) ? amax : 32 + amin;
    buckets[((size_t)(2 * wv + h) * BHN + bh) * T + t] = (unsigned char)bucket;
  }
}

// ---------------------------------------------------------------------------
// K2: stable counting argsort per (hash, bh) segment. grid (NH*BH), block 1024.
// ---------------------------------------------------------------------------
__global__ __launch_bounds__(1024) void k_sort(const unsigned char* __restrict__ buckets,
                                               int* __restrict__ perm) {
  __shared__ unsigned short bkt[T];
  __shared__ unsigned short rnk[T];
  __shared__ unsigned int cnt[64 * 64];
  __shared__ unsigned int bbase[64];
  __shared__ unsigned int btot[64];

  const int tid = threadIdx.x;
  const int seg = blockIdx.x;
  const unsigned char* bin = buckets + (size_t)seg * T;

  for (int idx = tid; idx < T; idx += 1024) bkt[idx] = bin[idx];
  __syncthreads();

  const int wave = tid >> 6, lane = tid & 63;
  const unsigned long long lt = (1ull << lane) - 1ull;
  for (int cc = 0; cc < 4; ++cc) {
    int chunk = wave * 4 + cc;
    int e = bkt[chunk * 64 + lane];
    for (int bb = 0; bb < 64; ++bb) {
      unsigned long long m = __ballot(e == bb);
      if (lane == bb) cnt[bb * 64 + chunk] = (unsigned int)__popcll(m);
      if (e == bb) rnk[chunk * 64 + lane] = (unsigned short)__popcll(m & lt);
    }
  }
  __syncthreads();
  if (tid < 64) {
    unsigned int run = 0;
    for (int c = 0; c < 64; ++c) {
      unsigned int v = cnt[tid * 64 + c];
      cnt[tid * 64 + c] = run;
      run += v;
    }
    btot[tid] = run;
  }
  __syncthreads();
  if (tid == 0) {
    unsigned int run = 0;
    for (int bb = 0; bb < 64; ++bb) { bbase[bb] = run; run += btot[bb]; }
  }
  __syncthreads();
  for (int idx = tid; idx < T; idx += 1024) {
    int e = bkt[idx];
    int c = idx >> 6;
    int pos = (int)(bbase[e] + cnt[e * 64 + c] + rnk[idx]);
    perm[(size_t)seg * T + pos] = idx;
  }
}

// ---------------------------------------------------------------------------
// K3: per-bucket attention, fp16, max-free softmax, UNNORMALIZED o_u output
// (exact combine: out = sum_r o_u[r] / sum_r l[r]). V path = proven register
// gather + v_perm transpose. LDS 32KB -> 5 blocks/CU. grid 8192 (XCD-swizzled).
// ---------------------------------------------------------------------------
__global__ __launch_bounds__(256, 5) void k_attn11(
    const unsigned short* __restrict__ khf, const unsigned short* __restrict__ vhf,
    const int* __restrict__ perm, const float* __restrict__ norm025,
    __half* __restrict__ o_ws, float* __restrict__ lsum_ws) {
  __shared__ __align__(16) char smem[32768];
  constexpr int LK  = 0;       // ph1: Khat [128 kv][128B fp16] SWZ128
  constexpr int LP  = 0;       // ph2: P [64 q][256B fp16 = 128 kv] SWZ256
  constexpr int LVT = 16384;   // V^T [64 d][256B fp16 = 128 tokens] SWZ256

  const int tid = threadIdx.x;
  // XCD-aware bijective swizzle (8192 % 8 == 0): XCD x gets hash r = x.
  const int wg = ((int)blockIdx.x & 7) * 1024 + ((int)blockIdx.x >> 3);
  const int n = wg & 63, bh = (wg >> 6) & 15, r = wg >> 10;
  const size_t rowbase = (size_t)bh * T;
  const size_t ps = ((size_t)r * BHN + bh) * T;
  const int base_own = n * 64;
  const int base_prev = ((n + 63) & 63) * 64;

  const int wid = tid >> 6, lane = tid & 63;
  const int lr = lane & 15, lg = lane >> 4;

  const int qtok = perm[ps + base_own + 16 * wid + lr];
  const float scale = norm025[rowbase + qtok];

  // ---- V gather: 2 tokens x 16 d per thread (issue early, in flight) ----
  const int vj0 = (tid & 63) * 2;         // token pair (vj0, vj0+1)
  const int vd0 = (tid >> 6) * 16;        // d range [vd0, vd0+16)
  int vt[2];
  #pragma unroll
  for (int j = 0; j < 2; ++j) {
    int src = (vj0 + j < 64) ? (base_own + vj0 + j) : (base_prev + vj0 + j - 64);
    vt[j] = perm[ps + src];
  }
  uint4 VA0, VA1, VB0, VB1;
  {
    const uint4* pa = (const uint4*)&vhf[(rowbase + (size_t)vt[0]) * 64 + vd0];
    const uint4* pb = (const uint4*)&vhf[(rowbase + (size_t)vt[1]) * 64 + vd0];
    VA0 = pa[0]; VA1 = pa[1];
    VB0 = pb[0]; VB1 = pb[1];
  }

  // ---- K staging: global_load_lds, linear dest + inverse-swizzled source ----
  #pragma unroll
  for (int it = 0; it < 4; ++it) {
    int unit = it * 256 + tid;
    int row = unit >> 3, sl = unit & 7;
    int ssl = sl ^ (row & 7);
    int src = (row < 64) ? (base_own + row) : (base_prev + (row - 64));
    int tokr = perm[ps + src];
    async_load16(&khf[(rowbase + (size_t)tokr) * 64 + ssl * 8], smem + LK + unit * 16);
  }
  __syncthreads();  // s2: K staged

  // B frag = own q row, held in regs before P overlays LK
  f16x8 bq[2];
  #pragma unroll
  for (int ks = 0; ks < 2; ++ks)
    bq[ks] = *(const f16x8*)(smem + LK + SWZ128(16 * wid + lr, lg * 16 + ks * 64));

  // ---- QK: S^T[kv][q] = K . Q^T, 16 MFMA ----
  f32x4 c[8];
  #pragma unroll
  for (int t = 0; t < 8; ++t) c[t] = (f32x4){0.f, 0.f, 0.f, 0.f};
  #pragma unroll
  for (int t = 0; t < 8; ++t) {
    #pragma unroll
    for (int ks = 0; ks < 2; ++ks) {
      f16x8 ak = *(const f16x8*)(smem + LK + SWZ128(16 * t + lr, lg * 16 + ks * 64));
      c[t] = mfma16f(ak, bq[ks], c[t]);
    }
  }

  // ---- V^T -> LVT (fresh region, hidden under QK; read only after s4) ----
  #pragma unroll
  for (int dd = 0; dd < 16; ++dd) {
    unsigned aw = (dd < 8) ? u4get(VA0, dd >> 1) : u4get(VA1, (dd - 8) >> 1);
    unsigned bw = (dd < 8) ? u4get(VB0, dd >> 1) : u4get(VB1, (dd - 8) >> 1);
    unsigned w = (dd & 1) ? __builtin_amdgcn_perm(bw, aw, 0x07060302u)
                          : __builtin_amdgcn_perm(bw, aw, 0x05040100u);
    *(unsigned*)(smem + LVT + SWZ256(vd0 + dd, vj0 * 2)) = w;
  }

  // ---- self-mask: position diagonal (q row == kv row in 0..63) ----
  #pragma unroll
  for (int t = 0; t < 4; ++t) {
    #pragma unroll
    for (int rr = 0; rr < 4; ++rr)
      if (16 * t + 4 * lg + rr == 16 * wid + lr) c[t][rr] = -1e30f;
  }

  // ---- MAX-FREE softmax: |score| <= scale (<= ~1.5), no overflow ----
  const float sl2e = scale * 1.4426950408889634f;
  float ll = 0.f;
  #pragma unroll
  for (int t = 0; t < 8; ++t) {
    #pragma unroll
    for (int rr = 0; rr < 4; ++rr) {
      float e = exp2f(c[t][rr] * sl2e);
      c[t][rr] = e;
      ll += e;
    }
  }
  ll += __shfl_xor(ll, 16);
  ll += __shfl_xor(ll, 32);
  if (lg == 0) lsum_ws[ps + qtok] = ll;   // raw sum (no log)

  __syncthreads();  // s3: all LK reads done

  // ---- P (unnormalized fp16, RTZ pack) over LK as [64 q][256B] ----
  {
    const int prow = 16 * wid + lr;
    #pragma unroll
    for (int t = 0; t < 8; ++t) {
      unsigned u01 = cvtpk_f16(c[t][0], c[t][1]);
      unsigned u23 = cvtpk_f16(c[t][2], c[t][3]);
      *(uint2*)(smem + LP + SWZ256(prow, 32 * t + 8 * lg)) = make_uint2(u01, u23);
    }
  }
  __syncthreads();  // s4: P + V^T staged

  // ---- PV: A = P row (q = 16w+lr), B = V^T rows (d), 16 MFMA ----
  f16x8 pa[4];
  #pragma unroll
  for (int ks = 0; ks < 4; ++ks)
    pa[ks] = *(const f16x8*)(smem + LP + SWZ256(16 * wid + lr, ks * 64 + lg * 16));
  f32x4 o[4];
  #pragma unroll
  for (int td = 0; td < 4; ++td) o[td] = (f32x4){0.f, 0.f, 0.f, 0.f};
  #pragma unroll
  for (int td = 0; td < 4; ++td) {
    #pragma unroll
    for (int ks = 0; ks < 4; ++ks) {
      f16x8 bv = *(const f16x8*)(smem + LVT + SWZ256(16 * td + lr, lg * 16 + ks * 64));
      o[td] = mfma16f(pa[ks], bv, o[td]);
    }
  }

  // ---- UNNORMALIZED fp16 O stores (otok via shuffle from qtok) ----
  #pragma unroll
  for (int rr = 0; rr < 4; ++rr) {
    int otok = __shfl(qtok, 4 * lg + rr);
    size_t gb = (ps + (size_t)otok) * 64 + lr;
    #pragma unroll
    for (int td = 0; td < 4; ++td)
      o_ws[gb + 16 * td] = __float2half(o[td][rr]);
  }
}

// ---------------------------------------------------------------------------
// K4: exact combine: out = (sum_r o_u[r]) / (sum_r l[r]). grid (BH*T*16/256).
// ---------------------------------------------------------------------------
__global__ __launch_bounds__(256) void k_combine(const __half* __restrict__ o_ws,
                                                 const float* __restrict__ lsum_ws,
                                                 float* __restrict__ out) {
  const int gid = blockIdx.x * 256 + threadIdx.x;
  const int d4 = (gid & 15) * 4;
  const int row = gid >> 4;   // bh*T + t
  const int bh = row >> 12;
  const int t = row & (T - 1);

  float lsum = 0.f;
  #pragma unroll
  for (int r = 0; r < 8; ++r)
    lsum += lsum_ws[((size_t)r * BHN + bh) * T + t];
  float rcp = 1.0f / lsum;

  float a0 = 0.f, a1 = 0.f, a2 = 0.f, a3 = 0.f;
  #pragma unroll
  for (int r = 0; r < 8; ++r) {
    const __half* op = &o_ws[(((size_t)r * BHN + bh) * T + t) * 64 + d4];
    __half2 h01 = *(const __half2*)&op[0];
    __half2 h23 = *(const __half2*)&op[2];
    float2 f01 = __half22float2(h01);
    float2 f23 = __half22float2(h23);
    a0 += f01.x; a1 += f01.y;
    a2 += f23.x; a3 += f23.y;
  }
  const int b = bh >> 3, hh = bh & 7;
  *(float4*)&out[(((size_t)b * T + t) * 8 + hh) * 64 + d4] =
      make_float4(a0 * rcp, a1 * rcp, a2 * rcp, a3 * rcp);
}

// ---------------------------------------------------------------------------
extern "C" void kernel_launch(void* const* d_in, const int* in_sizes, int n_in,
                              void* d_out, int out_size, void* d_ws, size_t ws_size,
                              hipStream_t stream) {
  const float* qk  = (const float*)d_in[0];
  const float* v   = (const float*)d_in[1];
  const float* rot = (const float*)d_in[2];
  float* out = (float*)d_out;

  // workspace layout (bytes) — total 95,158,272 (within proven budget)
  char* ws = (char*)d_ws;
  __half* o_ws          = (__half*)(ws);                      // 67,108,864
  int* perm             = (int*)(ws + 67108864);              //  8,388,608
  unsigned char* bkts   = (unsigned char*)(ws + 75497472);    //    524,288
  float* lsum_ws        = (float*)(ws + 76021760);            //  2,097,152
  float* norm025        = (float*)(ws + 78118912);            //    262,144
  unsigned short* khf   = (unsigned short*)(ws + 78381056);   //  8,388,608
  unsigned short* vhf   = (unsigned short*)(ws + 86769664);   //  8,388,608

  k_prepbkt<<<dim3(T / 64, BHN), 256, 0, stream>>>(qk, v, rot, khf, vhf, norm025, bkts);
  k_sort<<<dim3(NH * BHN), 1024, 0, stream>>>(bkts, perm);
  k_attn11<<<dim3(NB * BHN * NH), 256, 0, stream>>>(khf, vhf, perm, norm025,
                                                    o_ws, lsum_ws);
  k_combine<<<dim3((BHN * T * 16) / 256), 256, 0, stream>>>(o_ws, lsum_ws, out);
}